// Round 1
// baseline (857.249 us; speedup 1.0000x reference)
//
#include <hip/hip_runtime.h>
#include <hip/hip_bf16.h>

typedef __attribute__((ext_vector_type(4))) float  f32x4;
typedef __attribute__((ext_vector_type(8))) __bf16 bf16x8;
typedef __attribute__((ext_vector_type(4))) __bf16 bf16x4;

constexpr int S_LEN = 2048, DMODEL = 3584, NH = 28, NKV = 4, HD = 128, NREP = 7;
constexpr float SCALE_Q = 0.08838834764831845f; // 128^-0.5

// ---------------- f32 -> bf16 convert, x4 vectorized ----------------
__global__ void cvt_kernel(const float* __restrict__ in, __bf16* __restrict__ out, int n4) {
  int i = blockIdx.x * blockDim.x + threadIdx.x;
  if (i >= n4) return;
  float4 v = reinterpret_cast<const float4*>(in)[i];
  bf16x4 o;
  o[0] = (__bf16)v.x; o[1] = (__bf16)v.y; o[2] = (__bf16)v.z; o[3] = (__bf16)v.w;
  reinterpret_cast<bf16x4*>(out)[i] = o;
}

// ---------------- GEMM: C = A @ B^T (+bias) (+RoPE) ----------------
// A: MxK bf16 row-major, Bw: NxK bf16 row-major (weight rows = output cols)
// MODE 0: f32 out, no bias. MODE 1: bf16 out + bias. MODE 2: bf16 out + bias + RoPE*scale.
#define GLDS16(gsrc, ldst)                                                              \
  __builtin_amdgcn_global_load_lds((const __attribute__((address_space(1))) void*)(gsrc),\
                                   (__attribute__((address_space(3))) void*)(ldst), 16, 0, 0)

template <int MODE>
__global__ __launch_bounds__(256) void gemm_bt(
    const __bf16* __restrict__ A, const __bf16* __restrict__ Bw,
    const float* __restrict__ bias, void* __restrict__ Cout,
    int M, int N, int K,
    const float* __restrict__ fcos, const float* __restrict__ fsin,
    const int* __restrict__ sp_ptr, float scale)
{
  __shared__ __bf16 As[128 * 32];
  __shared__ __bf16 Bs[128 * 32];
  const int tid = threadIdx.x;
  const int lane = tid & 63, wid = tid >> 6;
  const int l15 = lane & 15, g = lane >> 4;
  const int wr = wid >> 1, wc = wid & 1;
  const int row0 = blockIdx.y * 128;
  const int col0 = blockIdx.x * 128;

  f32x4 acc[4][4] = {};

  // staging map: 16B chunk per thread per issue; row = tid>>2 (64B rows), col = (tid&3)*8
  const int srow = tid >> 2;
  const int scol = (tid & 3) * 8;
  const __bf16* Ag0 = A + (size_t)(row0 + srow) * K + scol;
  const __bf16* Ag1 = Ag0 + (size_t)64 * K;
  const __bf16* Bg0 = Bw + (size_t)(col0 + srow) * K + scol;
  const __bf16* Bg1 = Bg0 + (size_t)64 * K;
  __bf16* As0 = As + tid * 8;
  __bf16* As1 = As + 2048 + tid * 8;
  __bf16* Bs0 = Bs + tid * 8;
  __bf16* Bs1 = Bs + 2048 + tid * 8;

  for (int k0 = 0; k0 < K; k0 += 32) {
    GLDS16(Ag0 + k0, As0);
    GLDS16(Ag1 + k0, As1);
    GLDS16(Bg0 + k0, Bs0);
    GLDS16(Bg1 + k0, Bs1);
    __syncthreads();
    bf16x8 af[4], bfr[4];
#pragma unroll
    for (int m = 0; m < 4; m++)
      af[m] = *reinterpret_cast<const bf16x8*>(As + (wr * 64 + m * 16 + l15) * 32 + g * 8);
#pragma unroll
    for (int n = 0; n < 4; n++)
      bfr[n] = *reinterpret_cast<const bf16x8*>(Bs + (wc * 64 + n * 16 + l15) * 32 + g * 8);
#pragma unroll
    for (int m = 0; m < 4; m++)
#pragma unroll
      for (int n = 0; n < 4; n++)
        acc[m][n] = __builtin_amdgcn_mfma_f32_16x16x32_bf16(af[m], bfr[n], acc[m][n], 0, 0, 0);
    __syncthreads();
  }

  int sp = 0;
  if constexpr (MODE == 2) sp = sp_ptr[0];

#pragma unroll
  for (int m = 0; m < 4; m++) {
#pragma unroll
    for (int n = 0; n < 4; n++) {
      const int col = col0 + wc * 64 + n * 16 + l15;
      float bval = 0.0f;
      if constexpr (MODE >= 1) bval = bias[col];
      f32x4 v = acc[m][n];
#pragma unroll
      for (int r = 0; r < 4; r++) {
        const int row = row0 + wr * 64 + m * 16 + 4 * g + r;
        float y = v[r] + bval;
        if constexpr (MODE == 2) {
          float p = __shfl_xor(y, 1);           // partner column of the rotary pair
          const int i = (col & (HD - 1)) >> 1;
          const int spos = sp + (row & (S_LEN - 1));
          const float c = fcos[spos * (HD / 2) + i];
          const float sn = fsin[spos * (HD / 2) + i];
          y = (col & 1) ? (p * sn + y * c) : (y * c - p * sn);
          y *= scale;
        }
        if constexpr (MODE == 0)
          reinterpret_cast<float*>(Cout)[(size_t)row * N + col] = y;
        else
          reinterpret_cast<__bf16*>(Cout)[(size_t)row * N + col] = (__bf16)y;
      }
    }
  }
}

// ---------------- V transpose: (B,S,KV,HD) bf16 -> (B,KV,HD,S) bf16 ----------------
__global__ void vtrans_kernel(const __bf16* __restrict__ Vg, __bf16* __restrict__ Vt) {
  __shared__ __bf16 t[32][33];
  const int bkv = blockIdx.z;
  const int b = bkv >> 2, kv = bkv & 3;
  const int s0 = blockIdx.x * 32, h0 = blockIdx.y * 32;
  const int tid = threadIdx.x;
#pragma unroll
  for (int c = 0; c < 4; c++) {
    int idx = c * 256 + tid;
    int sr = idx >> 5, hc = idx & 31;
    t[sr][hc] = Vg[(((size_t)b * S_LEN + s0 + sr) * NKV + kv) * HD + h0 + hc];
  }
  __syncthreads();
#pragma unroll
  for (int c = 0; c < 4; c++) {
    int idx = c * 256 + tid;
    int hr = idx >> 5, sc = idx & 31;
    Vt[(((size_t)b * NKV + kv) * HD + h0 + hr) * S_LEN + s0 + sc] = t[sc][hr];
  }
}

// ---------------- Flash attention (causal, GQA) ----------------
// Qb: (B,S,H,HD) bf16 pre-scaled; Kb: (B,S,KV,HD) bf16; Vt: (B,KV,HD,S) bf16
// Ob: (B,S,H*HD) bf16.  Block: 4 waves x 16 q-rows = 64 q-rows. KV tile = 32.
__global__ __launch_bounds__(256) void attn_kernel(
    const __bf16* __restrict__ Qb, const __bf16* __restrict__ Kb,
    const __bf16* __restrict__ Vt, __bf16* __restrict__ Ob)
{
  __shared__ __bf16 Ks[32 * 128];  // K tile, xor-swizzled 256B rows
  __shared__ __bf16 Vs[128 * 32];  // V^T tile, xor-swizzled 64B rows
  const int tid = threadIdx.x, lane = tid & 63, wid = tid >> 6;
  const int l15 = lane & 15, g = lane >> 4;
  const int b = blockIdx.z, h = blockIdx.y;
  const int kvh = h / NREP;
  const int q0 = blockIdx.x * 64;
  const int qw = q0 + wid * 16;
  const int qrow = qw + l15;

  // Q fragments (B-operand of swapped QK^T): lane holds Q[q=l15][dc*32 + g*8 ..+8]
  bf16x8 qf[4];
  {
    const __bf16* qp = Qb + (((size_t)b * S_LEN + qw + l15) * NH + h) * HD;
#pragma unroll
    for (int dc = 0; dc < 4; dc++)
      qf[dc] = *reinterpret_cast<const bf16x8*>(qp + dc * 32 + g * 8);
  }

  f32x4 o[8] = {};               // O^T frags: o[dt][r] = O^T[dt*16+4g+r][q=l15]
  float mrun = -3.0e38f, lsum = 0.0f;

  const int ntiles = q0 / 32 + 2;  // causal: kv cols < q0+64
  const __bf16* Kbase = Kb + ((size_t)b * S_LEN * NKV + kvh) * HD;
  const __bf16* Vbase = Vt + ((size_t)b * NKV + kvh) * (size_t)HD * S_LEN;

  for (int t = 0; t < ntiles; t++) {
    const int k0 = t * 32;
    // stage K tile: 32 rows x 128, swizzle byte ^= (row&7)<<4
#pragma unroll
    for (int c = 0; c < 2; c++) {
      int idx = c * 256 + tid;
      int row = idx >> 4, col = idx & 15;
      const __bf16* src = Kbase + (size_t)(k0 + row) * (NKV * HD) + col * 8;
      int dstB = (row * 256 + col * 16) ^ ((row & 7) << 4);
      *reinterpret_cast<uint4*>(reinterpret_cast<char*>(Ks) + dstB) =
          *reinterpret_cast<const uint4*>(src);
    }
    // stage V^T tile: 128 rows x 32, swizzle byte ^= (d&3)<<4
#pragma unroll
    for (int c = 0; c < 2; c++) {
      int idx = c * 256 + tid;
      int d = idx >> 2, k8 = idx & 3;
      const __bf16* src = Vbase + (size_t)d * S_LEN + k0 + k8 * 8;
      int dstB = (d * 64 + k8 * 16) ^ ((d & 3) << 4);
      *reinterpret_cast<uint4*>(reinterpret_cast<char*>(Vs) + dstB) =
          *reinterpret_cast<const uint4*>(src);
    }
    __syncthreads();

    // S^T = K . Q^T : lane holds S[q=l15][k0 + st*16 + 4g + r]
    f32x4 sacc[2] = {};
#pragma unroll
    for (int st = 0; st < 2; st++) {
      const int row = st * 16 + l15;
#pragma unroll
      for (int dc = 0; dc < 4; dc++) {
        int off = (row * 256 + dc * 64 + g * 16) ^ ((row & 7) << 4);
        bf16x8 kf = *reinterpret_cast<const bf16x8*>(reinterpret_cast<const char*>(Ks) + off);
        sacc[st] = __builtin_amdgcn_mfma_f32_16x16x32_bf16(kf, qf[dc], sacc[st], 0, 0, 0);
      }
    }

    // causal mask + online softmax (rows spread over 4 lanes: shfl_xor 16/32 reduce)
    float pv[2][4];
    float pmax = -3.0e38f;
#pragma unroll
    for (int st = 0; st < 2; st++)
#pragma unroll
      for (int r = 0; r < 4; r++) {
        int kcol = k0 + st * 16 + 4 * g + r;
        float s = (kcol > qrow) ? -1.0e9f : sacc[st][r];
        pv[st][r] = s;
        pmax = fmaxf(pmax, s);
      }
    pmax = fmaxf(pmax, __shfl_xor(pmax, 16));
    pmax = fmaxf(pmax, __shfl_xor(pmax, 32));
    const float mnew = fmaxf(mrun, pmax);
    const float fs = __expf(mrun - mnew);
    float psum = 0.0f;
#pragma unroll
    for (int st = 0; st < 2; st++)
#pragma unroll
      for (int r = 0; r < 4; r++) {
        float e = __expf(pv[st][r] - mnew);
        pv[st][r] = e;
        psum += e;
      }
    psum += __shfl_xor(psum, 16);
    psum += __shfl_xor(psum, 32);
    lsum = lsum * fs + psum;
    mrun = mnew;
#pragma unroll
    for (int dt = 0; dt < 8; dt++) o[dt] *= fs;

    // Build P^T B-fragment in-register: pf[j] = P[q=l15][8g+j]
    // source lane = l15 + 16*(2*(g&1) + (j>>2)), tile = g>>1, reg = j&3
    bf16x8 pf;
    {
      const int srcbase = l15 + 32 * (g & 1);
      const bool hi = (g >> 1) != 0;
#pragma unroll
      for (int jj = 0; jj < 2; jj++) {
        const int src = srcbase + 16 * jj;
#pragma unroll
        for (int r = 0; r < 4; r++) {
          float p0 = __shfl(pv[0][r], src);
          float p1 = __shfl(pv[1][r], src);
          pf[jj * 4 + r] = (__bf16)(hi ? p1 : p0);
        }
      }
    }

    // O^T += V^T . P^T
#pragma unroll
    for (int dt = 0; dt < 8; dt++) {
      const int d = dt * 16 + l15;
      int off = (d * 64 + g * 16) ^ ((d & 3) << 4);
      bf16x8 vf = *reinterpret_cast<const bf16x8*>(reinterpret_cast<const char*>(Vs) + off);
      o[dt] = __builtin_amdgcn_mfma_f32_16x16x32_bf16(vf, pf, o[dt], 0, 0, 0);
    }
    __syncthreads();
  }

  const float inv = 1.0f / lsum;
  __bf16* op = Ob + (((size_t)b * S_LEN + qw + l15) * NH + h) * HD;
#pragma unroll
  for (int dt = 0; dt < 8; dt++) {
    bf16x4 pk;
#pragma unroll
    for (int r = 0; r < 4; r++) pk[r] = (__bf16)(o[dt][r] * inv);
    *reinterpret_cast<bf16x4*>(op + dt * 16 + 4 * g) = pk;  // d = dt*16 + 4g + r
  }
}

// ---------------- launch ----------------
extern "C" void kernel_launch(void* const* d_in, const int* in_sizes, int n_in,
                              void* d_out, int out_size, void* d_ws, size_t ws_size,
                              hipStream_t stream) {
  (void)in_sizes; (void)n_in; (void)out_size; (void)ws_size;
  const float* x    = (const float*)d_in[0];
  const float* wq_w = (const float*)d_in[1];
  const float* wq_b = (const float*)d_in[2];
  const float* wk_w = (const float*)d_in[3];
  const float* wk_b = (const float*)d_in[4];
  const float* wv_w = (const float*)d_in[5];
  const float* wv_b = (const float*)d_in[6];
  const float* wo_w = (const float*)d_in[7];
  const float* fcos = (const float*)d_in[10];
  const float* fsin = (const float*)d_in[11];
  const int*   spp  = (const int*)d_in[13];
  float* out = (float*)d_out;

  constexpr size_t XB_N = (size_t)4096 * 3584;   // x / O (bf16)
  constexpr size_t WQ_N = (size_t)3584 * 3584;
  constexpr size_t WK_N = (size_t)512 * 3584;
  constexpr size_t WO_N = (size_t)3584 * 3584;
  constexpr size_t KB_N = (size_t)4096 * 512;

  __bf16* xb  = (__bf16*)d_ws;
  __bf16* wqb = xb + XB_N;
  __bf16* wkb = wqb + WQ_N;
  __bf16* wvb = wkb + WK_N;
  __bf16* wob = wvb + WK_N;
  __bf16* Qb  = wob + WO_N;
  __bf16* Kb  = Qb + XB_N;
  __bf16* Vg  = Kb + KB_N;
  __bf16* Vt  = Vg + KB_N;
  __bf16* Ob  = xb;  // alias: xb is dead after the QKV GEMMs (stream-ordered)

  auto cvt = [&](const float* src, __bf16* dst, size_t n) {
    int n4 = (int)(n / 4);
    cvt_kernel<<<(n4 + 255) / 256, 256, 0, stream>>>(src, dst, n4);
  };
  cvt(x, xb, XB_N);
  cvt(wq_w, wqb, WQ_N);
  cvt(wk_w, wkb, WK_N);
  cvt(wv_w, wvb, WK_N);
  cvt(wo_w, wob, WO_N);

  gemm_bt<2><<<dim3(28, 32), 256, 0, stream>>>(xb, wqb, wq_b, Qb, 4096, 3584, 3584,
                                               fcos, fsin, spp, SCALE_Q);
  gemm_bt<2><<<dim3(4, 32), 256, 0, stream>>>(xb, wkb, wk_b, Kb, 4096, 512, 3584,
                                              fcos, fsin, spp, 1.0f);
  gemm_bt<1><<<dim3(4, 32), 256, 0, stream>>>(xb, wvb, wv_b, Vg, 4096, 512, 3584,
                                              nullptr, nullptr, nullptr, 1.0f);
  vtrans_kernel<<<dim3(64, 4, 8), 256, 0, stream>>>(Vg, Vt);
  attn_kernel<<<dim3(32, 28, 2), 256, 0, stream>>>(Qb, Kb, Vt, Ob);
  gemm_bt<0><<<dim3(28, 32), 256, 0, stream>>>(Ob, wob, nullptr, out, 4096, 3584, 3584,
                                               nullptr, nullptr, nullptr, 1.0f);
}

// Round 2
// 742.586 us; speedup vs baseline: 1.1544x; 1.1544x over previous
//
#include <hip/hip_runtime.h>
#include <hip/hip_bf16.h>

typedef __attribute__((ext_vector_type(4)))  float  f32x4;
typedef __attribute__((ext_vector_type(16))) float  f32x16;
typedef __attribute__((ext_vector_type(8)))  __bf16 bf16x8;
typedef __attribute__((ext_vector_type(4)))  __bf16 bf16x4;
typedef __attribute__((ext_vector_type(4)))  unsigned int u32x4;

constexpr int S_LEN = 2048, DMODEL = 3584, NH = 28, NKV = 4, HD = 128, NREP = 7;
// 128^-0.5 * log2(e): softmax computed in base-2 (exp2f == bare v_exp_f32)
constexpr float SCALE_LOG2 = 0.1275174331f;

__device__ __forceinline__ unsigned int pack2(float a, float b) {
  unsigned short ua = __builtin_bit_cast(unsigned short, (__bf16)a);
  unsigned short ub = __builtin_bit_cast(unsigned short, (__bf16)b);
  return (unsigned int)ua | ((unsigned int)ub << 16);
}

// ---------------- f32 -> bf16 convert, x4 vectorized ----------------
__global__ void cvt_kernel(const float* __restrict__ in, __bf16* __restrict__ out, int n4) {
  int i = blockIdx.x * blockDim.x + threadIdx.x;
  if (i >= n4) return;
  float4 v = reinterpret_cast<const float4*>(in)[i];
  bf16x4 o;
  o[0] = (__bf16)v.x; o[1] = (__bf16)v.y; o[2] = (__bf16)v.z; o[3] = (__bf16)v.w;
  reinterpret_cast<bf16x4*>(out)[i] = o;
}

#define GLDS16(gsrc, ldst)                                                              \
  __builtin_amdgcn_global_load_lds((const __attribute__((address_space(1))) void*)(gsrc),\
                                   (__attribute__((address_space(3))) void*)(ldst), 16, 0, 0)

// ---------------- GEMM: C = A @ B^T (+bias) (+RoPE) ----------------
template <int MODE>
__global__ __launch_bounds__(256) void gemm_bt(
    const __bf16* __restrict__ A, const __bf16* __restrict__ Bw,
    const float* __restrict__ bias, void* __restrict__ Cout,
    int M, int N, int K,
    const float* __restrict__ fcos, const float* __restrict__ fsin,
    const int* __restrict__ sp_ptr, float scale)
{
  __shared__ __bf16 As[128 * 32];
  __shared__ __bf16 Bs[128 * 32];
  const int tid = threadIdx.x;
  const int lane = tid & 63, wid = tid >> 6;
  const int l15 = lane & 15, g = lane >> 4;
  const int wr = wid >> 1, wc = wid & 1;
  const int row0 = blockIdx.y * 128;
  const int col0 = blockIdx.x * 128;

  f32x4 acc[4][4] = {};

  const int srow = tid >> 2;
  const int scol = (tid & 3) * 8;
  const __bf16* Ag0 = A + (size_t)(row0 + srow) * K + scol;
  const __bf16* Ag1 = Ag0 + (size_t)64 * K;
  const __bf16* Bg0 = Bw + (size_t)(col0 + srow) * K + scol;
  const __bf16* Bg1 = Bg0 + (size_t)64 * K;
  __bf16* As0 = As + tid * 8;
  __bf16* As1 = As + 2048 + tid * 8;
  __bf16* Bs0 = Bs + tid * 8;
  __bf16* Bs1 = Bs + 2048 + tid * 8;

  for (int k0 = 0; k0 < K; k0 += 32) {
    GLDS16(Ag0 + k0, As0);
    GLDS16(Ag1 + k0, As1);
    GLDS16(Bg0 + k0, Bs0);
    GLDS16(Bg1 + k0, Bs1);
    __syncthreads();
    bf16x8 af[4], bfr[4];
#pragma unroll
    for (int m = 0; m < 4; m++)
      af[m] = *reinterpret_cast<const bf16x8*>(As + (wr * 64 + m * 16 + l15) * 32 + g * 8);
#pragma unroll
    for (int n = 0; n < 4; n++)
      bfr[n] = *reinterpret_cast<const bf16x8*>(Bs + (wc * 64 + n * 16 + l15) * 32 + g * 8);
#pragma unroll
    for (int m = 0; m < 4; m++)
#pragma unroll
      for (int n = 0; n < 4; n++)
        acc[m][n] = __builtin_amdgcn_mfma_f32_16x16x32_bf16(af[m], bfr[n], acc[m][n], 0, 0, 0);
    __syncthreads();
  }

  int sp = 0;
  if constexpr (MODE == 2) sp = sp_ptr[0];

#pragma unroll
  for (int m = 0; m < 4; m++) {
#pragma unroll
    for (int n = 0; n < 4; n++) {
      const int col = col0 + wc * 64 + n * 16 + l15;
      float bval = 0.0f;
      if constexpr (MODE >= 1) bval = bias[col];
      f32x4 v = acc[m][n];
#pragma unroll
      for (int r = 0; r < 4; r++) {
        const int row = row0 + wr * 64 + m * 16 + 4 * g + r;
        float y = v[r] + bval;
        if constexpr (MODE == 2) {
          float p = __shfl_xor(y, 1);
          const int i = (col & (HD - 1)) >> 1;
          const int spos = sp + (row & (S_LEN - 1));
          const float c = fcos[spos * (HD / 2) + i];
          const float sn = fsin[spos * (HD / 2) + i];
          y = (col & 1) ? (p * sn + y * c) : (y * c - p * sn);
          y *= scale;
        }
        if constexpr (MODE == 0)
          reinterpret_cast<float*>(Cout)[(size_t)row * N + col] = y;
        else
          reinterpret_cast<__bf16*>(Cout)[(size_t)row * N + col] = (__bf16)y;
      }
    }
  }
}

// ---------------- V transpose: (B,S,KV,HD) bf16 -> (B,KV,HD,S) bf16 ----------------
__global__ void vtrans_kernel(const __bf16* __restrict__ Vg, __bf16* __restrict__ Vt) {
  __shared__ __bf16 t[32][33];
  const int bkv = blockIdx.z;
  const int b = bkv >> 2, kv = bkv & 3;
  const int s0 = blockIdx.x * 32, h0 = blockIdx.y * 32;
  const int tid = threadIdx.x;
#pragma unroll
  for (int c = 0; c < 4; c++) {
    int idx = c * 256 + tid;
    int sr = idx >> 5, hc = idx & 31;
    t[sr][hc] = Vg[(((size_t)b * S_LEN + s0 + sr) * NKV + kv) * HD + h0 + hc];
  }
  __syncthreads();
#pragma unroll
  for (int c = 0; c < 4; c++) {
    int idx = c * 256 + tid;
    int hr = idx >> 5, sc = idx & 31;
    Vt[(((size_t)b * NKV + kv) * HD + h0 + hr) * S_LEN + s0 + sc] = t[sc][hr];
  }
}

// ---------------- Flash attention v2: 32x32 MFMA, 4 waves x 32 q, KVBLK=64 ----------------
// Qb: (B,S,H,HD) bf16 pre-scaled by SCALE*log2e; Kb: (B,S,KV,HD) bf16; Vt: (B,KV,HD,S) bf16
// Ob: (B,S,H*HD) bf16.
__global__ __launch_bounds__(256, 2) void attn_kernel(
    const __bf16* __restrict__ Qb, const __bf16* __restrict__ Kb,
    const __bf16* __restrict__ Vt, __bf16* __restrict__ Ob)
{
  __shared__ __align__(16) char smem[32768];
  __bf16* Ks = (__bf16*)smem;            // [64][128] bf16, xor-swizzled rows (256B)
  __bf16* Vs = (__bf16*)(smem + 16384);  // [128][64] bf16, xor-swizzled rows (128B)

  const int tid = threadIdx.x, lane = tid & 63, wid = tid >> 6;
  const int l31 = lane & 31, hh = lane >> 5;
  const int b = blockIdx.z, h = blockIdx.y;
  const int kvh = h / NREP;
  const int qi = 15 - blockIdx.x;        // biggest causal blocks first
  const int qw = qi * 128 + wid * 32;    // warp's first q row
  const int qg = qw + l31;               // lane's q row

  // Q fragments (B-operand): qf[c] = Q[qg][16c + 8hh .. +8]
  bf16x8 qf[8];
  {
    const __bf16* qp = Qb + (((size_t)b * S_LEN + qg) * NH + h) * HD + hh * 8;
#pragma unroll
    for (int c = 0; c < 8; c++) qf[c] = *reinterpret_cast<const bf16x8*>(qp + c * 16);
  }

  f32x16 o[4] = {};   // O^T: o[dt][r] = O^T[32dt + (r&3)+8(r>>2)+4hh][qg]
  float mrun = -3.0e38f, lsum = 0.0f;

  const __bf16* Kbase = Kb + ((size_t)b * S_LEN * NKV + kvh) * HD;
  const __bf16* Vbase = Vt + ((size_t)b * NKV + kvh) * (size_t)HD * S_LEN;

  // staging maps: linear LDS dest (lane-ordered), pre-swizzled global source (m173)
  const int trow = tid >> 4;                                  // K row within 16-row pass
  const int kcol = (((tid & 15) * 16) ^ ((trow & 7) << 4)) >> 1;
  const int vrow = tid >> 3;                                  // V row within 32-row pass
  const int vcol = (((tid & 7) * 16) ^ ((vrow & 7) << 4)) >> 1;

  const int ntiles = 2 * qi + 2;
  for (int t = 0; t < ntiles; t++) {
    const int k0 = t * 64;
#pragma unroll
    for (int p = 0; p < 4; p++) {
      GLDS16(Kbase + (size_t)(k0 + p * 16 + trow) * (NKV * HD) + kcol,
             Ks + (p * 256 + tid) * 8);
      GLDS16(Vbase + (size_t)(p * 32 + vrow) * S_LEN + k0 + vcol,
             Vs + (p * 256 + tid) * 8);
    }
    __syncthreads();

    // ---- S^T[kv 64][q 32] = K . Q^T
    f32x16 s0 = {}, s1 = {};
    {
      const char* kp0 = (const char*)Ks + l31 * 256;
      const char* kp1 = kp0 + 32 * 256;
      const int sw = (l31 & 7) << 4;
#pragma unroll
      for (int c = 0; c < 8; c++) {
        const int cb = (c * 32 + hh * 16) ^ sw;
        bf16x8 kf0 = *reinterpret_cast<const bf16x8*>(kp0 + cb);
        s0 = __builtin_amdgcn_mfma_f32_32x32x16_bf16(kf0, qf[c], s0, 0, 0, 0);
        bf16x8 kf1 = *reinterpret_cast<const bf16x8*>(kp1 + cb);
        s1 = __builtin_amdgcn_mfma_f32_32x32x16_bf16(kf1, qf[c], s1, 0, 0, 0);
      }
    }

    // ---- causal mask (boundary tiles only; wave-uniform branch)
    if (k0 + 63 > qw) {
#pragma unroll
      for (int r = 0; r < 16; r++) {
        const int kvo = k0 + ((r & 3) + 8 * (r >> 2)) + 4 * hh;
        if (kvo > qg)      s0[r] = -1.0e9f;
        if (kvo + 32 > qg) s1[r] = -1.0e9f;
      }
    }

    // ---- online softmax (base-2), defer-max (T13)
    float pmax = -3.0e38f;
#pragma unroll
    for (int r = 0; r < 16; r++) { pmax = fmaxf(pmax, s0[r]); pmax = fmaxf(pmax, s1[r]); }
    pmax = fmaxf(pmax, __shfl_xor(pmax, 32));
    if (!__all(pmax <= mrun + 11.5f)) {
      const float mnew = fmaxf(mrun, pmax);
      const float fs = exp2f(mrun - mnew);
      lsum *= fs;
#pragma unroll
      for (int dt = 0; dt < 4; dt++) o[dt] *= fs;
      mrun = mnew;
    }
    float psum = 0.0f;
#pragma unroll
    for (int r = 0; r < 16; r++) {
      s0[r] = exp2f(s0[r] - mrun); psum += s0[r];
      s1[r] = exp2f(s1[r] - mrun); psum += s1[r];
    }
    lsum += psum;

    // ---- pack P to bf16 pairs + cross-half exchange
    unsigned int pk[2][8], px[2][8];
#pragma unroll
    for (int j = 0; j < 8; j++) {
      pk[0][j] = pack2(s0[2 * j], s0[2 * j + 1]);
      pk[1][j] = pack2(s1[2 * j], s1[2 * j + 1]);
    }
#pragma unroll
    for (int tt = 0; tt < 2; tt++)
#pragma unroll
      for (int j = 0; j < 8; j++) px[tt][j] = __shfl_xor(pk[tt][j], 32);

    // ---- O^T += V^T . P^T
#pragma unroll
    for (int tt = 0; tt < 2; tt++) {
#pragma unroll
      for (int c2 = 0; c2 < 2; c2++) {
        u32x4 pb4;
        if (hh == 0)
          pb4 = (u32x4){pk[tt][4 * c2], pk[tt][4 * c2 + 1], px[tt][4 * c2], px[tt][4 * c2 + 1]};
        else
          pb4 = (u32x4){px[tt][4 * c2 + 2], px[tt][4 * c2 + 3], pk[tt][4 * c2 + 2], pk[tt][4 * c2 + 3]};
        bf16x8 pbf = __builtin_bit_cast(bf16x8, pb4);
        const int colb = tt * 64 + c2 * 32 + hh * 16;
#pragma unroll
        for (int dt = 0; dt < 4; dt++) {
          const int d = dt * 32 + l31;
          bf16x8 vf = *reinterpret_cast<const bf16x8*>(
              (const char*)Vs + d * 128 + (colb ^ ((d & 7) << 4)));
          o[dt] = __builtin_amdgcn_mfma_f32_32x32x16_bf16(vf, pbf, o[dt], 0, 0, 0);
        }
      }
    }
    __syncthreads();
  }

  // ---- epilogue: normalize, transpose O^T -> O via warp-local LDS, 16B stores
  lsum += __shfl_xor(lsum, 32);
  const float inv = 1.0f / lsum;
  char* my = smem + wid * 8192;  // [32 q][256B] per warp, xor-swizzled
#pragma unroll
  for (int dt = 0; dt < 4; dt++) {
#pragma unroll
    for (int j = 0; j < 8; j++) {
      const int r = 2 * j;
      const int d = dt * 32 + ((r & 3) + 8 * (r >> 2)) + 4 * hh;
      const unsigned int w = pack2(o[dt][r] * inv, o[dt][r + 1] * inv);
      *reinterpret_cast<unsigned int*>(my + ((l31 * 256 + d * 2) ^ ((l31 & 7) << 4))) = w;
    }
  }
  // wave-local producer/consumer: compiler orders via lgkmcnt, no barrier needed
#pragma unroll
  for (int j = 0; j < 8; j++) {
    const int idx = j * 64 + lane;
    const int row = idx >> 4, c16 = idx & 15;
    u32x4 val = *reinterpret_cast<u32x4*>(my + row * 256 + ((c16 * 16) ^ ((row & 7) << 4)));
    *reinterpret_cast<u32x4*>(Ob + (size_t)(b * S_LEN + qw + row) * (NH * HD) + h * HD + c16 * 8) = val;
  }
}

// ---------------- launch ----------------
extern "C" void kernel_launch(void* const* d_in, const int* in_sizes, int n_in,
                              void* d_out, int out_size, void* d_ws, size_t ws_size,
                              hipStream_t stream) {
  (void)in_sizes; (void)n_in; (void)out_size; (void)ws_size;
  const float* x    = (const float*)d_in[0];
  const float* wq_w = (const float*)d_in[1];
  const float* wq_b = (const float*)d_in[2];
  const float* wk_w = (const float*)d_in[3];
  const float* wk_b = (const float*)d_in[4];
  const float* wv_w = (const float*)d_in[5];
  const float* wv_b = (const float*)d_in[6];
  const float* wo_w = (const float*)d_in[7];
  const float* fcos = (const float*)d_in[10];
  const float* fsin = (const float*)d_in[11];
  const int*   spp  = (const int*)d_in[13];
  float* out = (float*)d_out;

  constexpr size_t XB_N = (size_t)4096 * 3584;   // x / O (bf16)
  constexpr size_t WQ_N = (size_t)3584 * 3584;
  constexpr size_t WK_N = (size_t)512 * 3584;
  constexpr size_t WO_N = (size_t)3584 * 3584;
  constexpr size_t KB_N = (size_t)4096 * 512;

  __bf16* xb  = (__bf16*)d_ws;
  __bf16* wqb = xb + XB_N;
  __bf16* wkb = wqb + WQ_N;
  __bf16* wvb = wkb + WK_N;
  __bf16* wob = wvb + WK_N;
  __bf16* Qb  = wob + WO_N;
  __bf16* Kb  = Qb + XB_N;
  __bf16* Vg  = Kb + KB_N;
  __bf16* Vt  = Vg + KB_N;
  __bf16* Ob  = xb;  // alias: xb dead after QKV GEMMs (stream-ordered)

  auto cvt = [&](const float* src, __bf16* dst, size_t n) {
    int n4 = (int)(n / 4);
    cvt_kernel<<<(n4 + 255) / 256, 256, 0, stream>>>(src, dst, n4);
  };
  cvt(x, xb, XB_N);
  cvt(wq_w, wqb, WQ_N);
  cvt(wk_w, wkb, WK_N);
  cvt(wv_w, wvb, WK_N);
  cvt(wo_w, wob, WO_N);

  gemm_bt<2><<<dim3(28, 32), 256, 0, stream>>>(xb, wqb, wq_b, Qb, 4096, 3584, 3584,
                                               fcos, fsin, spp, SCALE_LOG2);
  gemm_bt<2><<<dim3(4, 32), 256, 0, stream>>>(xb, wkb, wk_b, Kb, 4096, 512, 3584,
                                              fcos, fsin, spp, 1.0f);
  gemm_bt<1><<<dim3(4, 32), 256, 0, stream>>>(xb, wvb, wv_b, Vg, 4096, 512, 3584,
                                              nullptr, nullptr, nullptr, 1.0f);
  vtrans_kernel<<<dim3(64, 4, 8), 256, 0, stream>>>(Vg, Vt);
  attn_kernel<<<dim3(16, 28, 2), 256, 0, stream>>>(Qb, Kb, Vt, Ob);
  gemm_bt<0><<<dim3(28, 32), 256, 0, stream>>>(Ob, wob, nullptr, out, 4096, 3584, 3584,
                                               nullptr, nullptr, nullptr, 1.0f);
}

// Round 3
// 599.448 us; speedup vs baseline: 1.4301x; 1.2388x over previous
//
#include <hip/hip_runtime.h>
#include <hip/hip_bf16.h>

typedef __attribute__((ext_vector_type(4)))  float  f32x4;
typedef __attribute__((ext_vector_type(16))) float  f32x16;
typedef __attribute__((ext_vector_type(8)))  __bf16 bf16x8;
typedef __attribute__((ext_vector_type(4)))  __bf16 bf16x4;
typedef __attribute__((ext_vector_type(4)))  unsigned int u32x4;

constexpr int S_LEN = 2048, DMODEL = 3584, NH = 28, NKV = 4, HD = 128, NREP = 7;
// 128^-0.5 * log2(e): softmax computed in base-2 (exp2f == bare v_exp_f32)
constexpr float SCALE_LOG2 = 0.1275174331f;

__device__ __forceinline__ unsigned int pack2(float a, float b) {
  unsigned short ua = __builtin_bit_cast(unsigned short, (__bf16)a);
  unsigned short ub = __builtin_bit_cast(unsigned short, (__bf16)b);
  return (unsigned int)ua | ((unsigned int)ub << 16);
}

// ---------------- f32 -> bf16 convert, x4 vectorized ----------------
__global__ void cvt_kernel(const float* __restrict__ in, __bf16* __restrict__ out, int n4) {
  int i = blockIdx.x * blockDim.x + threadIdx.x;
  if (i >= n4) return;
  float4 v = reinterpret_cast<const float4*>(in)[i];
  bf16x4 o;
  o[0] = (__bf16)v.x; o[1] = (__bf16)v.y; o[2] = (__bf16)v.z; o[3] = (__bf16)v.w;
  reinterpret_cast<bf16x4*>(out)[i] = o;
}

#define GLDS16(gsrc, ldst)                                                              \
  __builtin_amdgcn_global_load_lds((const __attribute__((address_space(1))) void*)(gsrc),\
                                   (__attribute__((address_space(3))) void*)(ldst), 16, 0, 0)

// ============ 256x256 phased GEMM: C = A @ B^T (+bias) (+RoPE) ============
// A: MxK bf16 rm, Bw: NxK bf16 rm. MODE 0: f32 out. MODE 2: bf16 out + bias + RoPE*scale.
// 8 waves (2M x 4N), BK=32, 4-slot LDS ring (128 KiB), counted vmcnt(8), st_16x32 swizzle.
template <int MODE>
__global__ __launch_bounds__(512, 2) void gemm256(
    const __bf16* __restrict__ A, const __bf16* __restrict__ Bw,
    const float* __restrict__ bias, void* __restrict__ Cout,
    int M, int N, int K,
    const float* __restrict__ fcos, const float* __restrict__ fsin,
    const int* __restrict__ sp_ptr, float scale)
{
  extern __shared__ char smem[];  // [0,64K): A slots[4][16K]; [64K,128K): B slots[4][16K]
  const int tid = threadIdx.x;
  const int lane = tid & 63, wid = tid >> 6;
  const int wm = wid >> 2, wn = wid & 3;
  const int l15 = lane & 15, g = (lane >> 4) & 3;

  // bijective XCD chunking (gridDim.x % 8 == 0)
  const int chunk = gridDim.x >> 3;
  const int wg = (blockIdx.x & 7) * chunk + (blockIdx.x >> 3);
  const int nbx = N >> 8;
  const int by = wg / nbx, bx = wg % nbx;
  const int row0 = by * 256, col0 = bx * 256;

  // ---- staging maps (pre-swizzled global source; linear GLDS dest) ----
  // LDS half-pass layout: subtile sr=r>>4 (1024B), within: (r&15)*64 + (c*2 ^ ((r&8)<<2))
  const int srL   = 16 * (tid >> 6) + ((tid >> 2) & 15);            // row in 128-row pass
  const int cperm = ((tid & 3) * 8) ^ (((tid >> 5) & 1) * 16);      // permuted col element
  const __bf16* pA0 = A + (size_t)(row0 + srL) * K + cperm;
  const __bf16* pA1 = pA0 + (size_t)128 * K;
  const __bf16* pB0 = Bw + (size_t)(col0 + srL) * K + cperm;
  const __bf16* pB1 = pB0 + (size_t)128 * K;
  char* ldsA = smem + tid * 16;            // + slot*16384 + pass*8192
  char* ldsB = smem + 65536 + tid * 16;

  // ---- fragment read bases ----
  const int sw = ((l15 >> 3) & 1) << 5;
  const int aoff = wm * 8192 + l15 * 64 + ((g * 16) ^ sw);          // + fm*1024 + slot*16384
  const int boff = 65536 + wn * 4096 + l15 * 64 + ((g * 16) ^ sw);  // + fn*1024 + slot*16384

  f32x4 acc[8][4] = {};
  const int nt = K >> 5;  // K-tiles of 32

  // ---- prologue: stage tiles 0,1,2 (12 loads) ----
#pragma unroll
  for (int pt = 0; pt < 3; pt++) {
    const size_t ko = (size_t)pt * 32;
    char* sA = ldsA + pt * 16384;
    char* sB = ldsB + pt * 16384;
    GLDS16(pA0 + ko, sA);
    GLDS16(pA1 + ko, sA + 8192);
    GLDS16(pB0 + ko, sB);
    GLDS16(pB1 + ko, sB + 8192);
  }
  asm volatile("s_waitcnt vmcnt(8)" ::: "memory");   // tile 0 resident
  __builtin_amdgcn_s_barrier();
  __builtin_amdgcn_sched_barrier(0);

  for (int t = 0; t < nt; t++) {
    const int slot = (t & 3) * 16384;
    const char* sa = smem + slot + aoff;
    const char* sb = smem + slot + boff;
    bf16x8 af[4], bfv[4];

    // ===== phase 0: quadrant mh=0 =====
#pragma unroll
    for (int fm = 0; fm < 4; fm++)
      af[fm] = *reinterpret_cast<const bf16x8*>(sa + fm * 1024);
#pragma unroll
    for (int fn = 0; fn < 4; fn++)
      bfv[fn] = *reinterpret_cast<const bf16x8*>(sb + fn * 1024);
    if (t + 3 < nt) {  // stage A of tile t+3 into slot (t+3)&3 == (t-1)&3 (no live readers)
      const size_t ko = (size_t)(t + 3) * 32;
      char* sA = ldsA + ((t + 3) & 3) * 16384;
      GLDS16(pA0 + ko, sA);
      GLDS16(pA1 + ko, sA + 8192);
    }
    asm volatile("s_waitcnt lgkmcnt(0)" ::: "memory");
    __builtin_amdgcn_sched_barrier(0);
    __builtin_amdgcn_s_setprio(1);
#pragma unroll
    for (int fn = 0; fn < 4; fn++)
#pragma unroll
      for (int fm = 0; fm < 4; fm++)
        acc[fm][fn] = __builtin_amdgcn_mfma_f32_16x16x32_bf16(af[fm], bfv[fn], acc[fm][fn], 0, 0, 0);
    __builtin_amdgcn_s_setprio(0);
    __builtin_amdgcn_s_barrier();
    __builtin_amdgcn_sched_barrier(0);

    // ===== phase 1: quadrant mh=1 (B-frags reused) =====
#pragma unroll
    for (int fm = 0; fm < 4; fm++)
      af[fm] = *reinterpret_cast<const bf16x8*>(sa + (4 + fm) * 1024);
    if (t + 3 < nt) {  // stage B of tile t+3
      const size_t ko = (size_t)(t + 3) * 32;
      char* sB = ldsB + ((t + 3) & 3) * 16384;
      GLDS16(pB0 + ko, sB);
      GLDS16(pB1 + ko, sB + 8192);
    }
    asm volatile("s_waitcnt lgkmcnt(0)" ::: "memory");
    __builtin_amdgcn_sched_barrier(0);
    __builtin_amdgcn_s_setprio(1);
#pragma unroll
    for (int fn = 0; fn < 4; fn++)
#pragma unroll
      for (int fm = 0; fm < 4; fm++)
        acc[4 + fm][fn] = __builtin_amdgcn_mfma_f32_16x16x32_bf16(af[fm], bfv[fn], acc[4 + fm][fn], 0, 0, 0);
    __builtin_amdgcn_s_setprio(0);

    // ---- tile boundary: counted drain (tile t+1 must be resident; keep 8 in flight) ----
    if (t < nt - 3)       asm volatile("s_waitcnt vmcnt(8)" ::: "memory");
    else if (t == nt - 3) asm volatile("s_waitcnt vmcnt(4)" ::: "memory");
    else if (t == nt - 2) asm volatile("s_waitcnt vmcnt(0)" ::: "memory");
    __builtin_amdgcn_s_barrier();
    __builtin_amdgcn_sched_barrier(0);
  }

  // ---- epilogue ----
  if constexpr (MODE == 0) {
    float* C = (float*)Cout;
#pragma unroll
    for (int fm = 0; fm < 8; fm++) {
      const int row = row0 + wm * 128 + fm * 16 + 4 * g;
#pragma unroll
      for (int fn = 0; fn < 4; fn++) {
        const int col = col0 + wn * 64 + fn * 16 + l15;
#pragma unroll
        for (int r = 0; r < 4; r++)
          C[(size_t)(row + r) * N + col] = acc[fm][fn][r];
      }
    }
  } else {
    __bf16* C = (__bf16*)Cout;
    const int sp = sp_ptr[0];
    float bval[4];
#pragma unroll
    for (int fn = 0; fn < 4; fn++) bval[fn] = bias[col0 + wn * 64 + fn * 16 + l15];
#pragma unroll
    for (int fm = 0; fm < 8; fm++) {
#pragma unroll
      for (int fn = 0; fn < 4; fn++) {
        const int col = col0 + wn * 64 + fn * 16 + l15;
        const int i = (col & (HD - 1)) >> 1;
#pragma unroll
        for (int r = 0; r < 4; r++) {
          const int row = row0 + wm * 128 + fm * 16 + 4 * g + r;
          float y = acc[fm][fn][r] + bval[fn];
          float p = __shfl_xor(y, 1);
          const int spos = sp + (row & (S_LEN - 1));
          const float c = fcos[spos * (HD / 2) + i];
          const float sn = fsin[spos * (HD / 2) + i];
          y = (col & 1) ? (p * sn + y * c) : (y * c - p * sn);
          C[(size_t)row * N + col] = (__bf16)(y * scale);
        }
      }
    }
  }
}

// ---------------- 128^2 GEMM (kept for K/V projections, N=512) ----------------
template <int MODE>
__global__ __launch_bounds__(256) void gemm_bt(
    const __bf16* __restrict__ A, const __bf16* __restrict__ Bw,
    const float* __restrict__ bias, void* __restrict__ Cout,
    int M, int N, int K,
    const float* __restrict__ fcos, const float* __restrict__ fsin,
    const int* __restrict__ sp_ptr, float scale)
{
  __shared__ __bf16 As[128 * 32];
  __shared__ __bf16 Bs[128 * 32];
  const int tid = threadIdx.x;
  const int lane = tid & 63, wid = tid >> 6;
  const int l15 = lane & 15, g = lane >> 4;
  const int wr = wid >> 1, wc = wid & 1;
  const int row0 = blockIdx.y * 128;
  const int col0 = blockIdx.x * 128;

  f32x4 acc[4][4] = {};

  const int srow = tid >> 2;
  const int scol = (tid & 3) * 8;
  const __bf16* Ag0 = A + (size_t)(row0 + srow) * K + scol;
  const __bf16* Ag1 = Ag0 + (size_t)64 * K;
  const __bf16* Bg0 = Bw + (size_t)(col0 + srow) * K + scol;
  const __bf16* Bg1 = Bg0 + (size_t)64 * K;
  __bf16* As0 = As + tid * 8;
  __bf16* As1 = As + 2048 + tid * 8;
  __bf16* Bs0 = Bs + tid * 8;
  __bf16* Bs1 = Bs + 2048 + tid * 8;

  for (int k0 = 0; k0 < K; k0 += 32) {
    GLDS16(Ag0 + k0, As0);
    GLDS16(Ag1 + k0, As1);
    GLDS16(Bg0 + k0, Bs0);
    GLDS16(Bg1 + k0, Bs1);
    __syncthreads();
    bf16x8 af[4], bfr[4];
#pragma unroll
    for (int m = 0; m < 4; m++)
      af[m] = *reinterpret_cast<const bf16x8*>(As + (wr * 64 + m * 16 + l15) * 32 + g * 8);
#pragma unroll
    for (int n = 0; n < 4; n++)
      bfr[n] = *reinterpret_cast<const bf16x8*>(Bs + (wc * 64 + n * 16 + l15) * 32 + g * 8);
#pragma unroll
    for (int m = 0; m < 4; m++)
#pragma unroll
      for (int n = 0; n < 4; n++)
        acc[m][n] = __builtin_amdgcn_mfma_f32_16x16x32_bf16(af[m], bfr[n], acc[m][n], 0, 0, 0);
    __syncthreads();
  }

  int sp = 0;
  if constexpr (MODE == 2) sp = sp_ptr[0];

#pragma unroll
  for (int m = 0; m < 4; m++) {
#pragma unroll
    for (int n = 0; n < 4; n++) {
      const int col = col0 + wc * 64 + n * 16 + l15;
      float bval = 0.0f;
      if constexpr (MODE >= 1) bval = bias[col];
      f32x4 v = acc[m][n];
#pragma unroll
      for (int r = 0; r < 4; r++) {
        const int row = row0 + wr * 64 + m * 16 + 4 * g + r;
        float y = v[r] + bval;
        if constexpr (MODE == 2) {
          float p = __shfl_xor(y, 1);
          const int i = (col & (HD - 1)) >> 1;
          const int spos = sp + (row & (S_LEN - 1));
          const float c = fcos[spos * (HD / 2) + i];
          const float sn = fsin[spos * (HD / 2) + i];
          y = (col & 1) ? (p * sn + y * c) : (y * c - p * sn);
          y *= scale;
        }
        if constexpr (MODE == 0)
          reinterpret_cast<float*>(Cout)[(size_t)row * N + col] = y;
        else
          reinterpret_cast<__bf16*>(Cout)[(size_t)row * N + col] = (__bf16)y;
      }
    }
  }
}

// ---------------- V transpose: (B,S,KV,HD) bf16 -> (B,KV,HD,S) bf16 ----------------
__global__ void vtrans_kernel(const __bf16* __restrict__ Vg, __bf16* __restrict__ Vt) {
  __shared__ __bf16 t[32][33];
  const int bkv = blockIdx.z;
  const int b = bkv >> 2, kv = bkv & 3;
  const int s0 = blockIdx.x * 32, h0 = blockIdx.y * 32;
  const int tid = threadIdx.x;
#pragma unroll
  for (int c = 0; c < 4; c++) {
    int idx = c * 256 + tid;
    int sr = idx >> 5, hc = idx & 31;
    t[sr][hc] = Vg[(((size_t)b * S_LEN + s0 + sr) * NKV + kv) * HD + h0 + hc];
  }
  __syncthreads();
#pragma unroll
  for (int c = 0; c < 4; c++) {
    int idx = c * 256 + tid;
    int hr = idx >> 5, sc = idx & 31;
    Vt[(((size_t)b * NKV + kv) * HD + h0 + hr) * S_LEN + s0 + sc] = t[sc][hr];
  }
}

// ---------------- Flash attention: 32x32 MFMA, 4 waves x 32 q, KVBLK=64 ----------------
__global__ __launch_bounds__(256, 2) void attn_kernel(
    const __bf16* __restrict__ Qb, const __bf16* __restrict__ Kb,
    const __bf16* __restrict__ Vt, __bf16* __restrict__ Ob)
{
  __shared__ __align__(16) char asmem[32768];
  __bf16* Ks = (__bf16*)asmem;            // [64][128] bf16, xor-swizzled rows (256B)
  __bf16* Vs = (__bf16*)(asmem + 16384);  // [128][64] bf16, xor-swizzled rows (128B)

  const int tid = threadIdx.x, lane = tid & 63, wid = tid >> 6;
  const int l31 = lane & 31, hh = lane >> 5;
  const int b = blockIdx.z, h = blockIdx.y;
  const int kvh = h / NREP;
  const int qi = 15 - blockIdx.x;
  const int qw = qi * 128 + wid * 32;
  const int qg = qw + l31;

  bf16x8 qf[8];
  {
    const __bf16* qp = Qb + (((size_t)b * S_LEN + qg) * NH + h) * HD + hh * 8;
#pragma unroll
    for (int c = 0; c < 8; c++) qf[c] = *reinterpret_cast<const bf16x8*>(qp + c * 16);
  }

  f32x16 o[4] = {};
  float mrun = -3.0e38f, lsum = 0.0f;

  const __bf16* Kbase = Kb + ((size_t)b * S_LEN * NKV + kvh) * HD;
  const __bf16* Vbase = Vt + ((size_t)b * NKV + kvh) * (size_t)HD * S_LEN;

  const int trow = tid >> 4;
  const int kcol = (((tid & 15) * 16) ^ ((trow & 7) << 4)) >> 1;
  const int vrow = tid >> 3;
  const int vcol = (((tid & 7) * 16) ^ ((vrow & 7) << 4)) >> 1;

  const int ntiles = 2 * qi + 2;
  for (int t = 0; t < ntiles; t++) {
    const int k0 = t * 64;
#pragma unroll
    for (int p = 0; p < 4; p++) {
      GLDS16(Kbase + (size_t)(k0 + p * 16 + trow) * (NKV * HD) + kcol,
             Ks + (p * 256 + tid) * 8);
      GLDS16(Vbase + (size_t)(p * 32 + vrow) * S_LEN + k0 + vcol,
             Vs + (p * 256 + tid) * 8);
    }
    __syncthreads();

    f32x16 s0 = {}, s1 = {};
    {
      const char* kp0 = (const char*)Ks + l31 * 256;
      const char* kp1 = kp0 + 32 * 256;
      const int sw = (l31 & 7) << 4;
#pragma unroll
      for (int c = 0; c < 8; c++) {
        const int cb = (c * 32 + hh * 16) ^ sw;
        bf16x8 kf0 = *reinterpret_cast<const bf16x8*>(kp0 + cb);
        s0 = __builtin_amdgcn_mfma_f32_32x32x16_bf16(kf0, qf[c], s0, 0, 0, 0);
        bf16x8 kf1 = *reinterpret_cast<const bf16x8*>(kp1 + cb);
        s1 = __builtin_amdgcn_mfma_f32_32x32x16_bf16(kf1, qf[c], s1, 0, 0, 0);
      }
    }

    if (k0 + 63 > qw) {
#pragma unroll
      for (int r = 0; r < 16; r++) {
        const int kvo = k0 + ((r & 3) + 8 * (r >> 2)) + 4 * hh;
        if (kvo > qg)      s0[r] = -1.0e9f;
        if (kvo + 32 > qg) s1[r] = -1.0e9f;
      }
    }

    float pmax = -3.0e38f;
#pragma unroll
    for (int r = 0; r < 16; r++) { pmax = fmaxf(pmax, s0[r]); pmax = fmaxf(pmax, s1[r]); }
    pmax = fmaxf(pmax, __shfl_xor(pmax, 32));
    if (!__all(pmax <= mrun + 11.5f)) {
      const float mnew = fmaxf(mrun, pmax);
      const float fs = exp2f(mrun - mnew);
      lsum *= fs;
#pragma unroll
      for (int dt = 0; dt < 4; dt++) o[dt] *= fs;
      mrun = mnew;
    }
    float psum = 0.0f;
#pragma unroll
    for (int r = 0; r < 16; r++) {
      s0[r] = exp2f(s0[r] - mrun); psum += s0[r];
      s1[r] = exp2f(s1[r] - mrun); psum += s1[r];
    }
    lsum += psum;

    unsigned int pk[2][8], px[2][8];
#pragma unroll
    for (int j = 0; j < 8; j++) {
      pk[0][j] = pack2(s0[2 * j], s0[2 * j + 1]);
      pk[1][j] = pack2(s1[2 * j], s1[2 * j + 1]);
    }
#pragma unroll
    for (int tt = 0; tt < 2; tt++)
#pragma unroll
      for (int j = 0; j < 8; j++) px[tt][j] = __shfl_xor(pk[tt][j], 32);

#pragma unroll
    for (int tt = 0; tt < 2; tt++) {
#pragma unroll
      for (int c2 = 0; c2 < 2; c2++) {
        u32x4 pb4;
        if (hh == 0)
          pb4 = (u32x4){pk[tt][4 * c2], pk[tt][4 * c2 + 1], px[tt][4 * c2], px[tt][4 * c2 + 1]};
        else
          pb4 = (u32x4){px[tt][4 * c2 + 2], px[tt][4 * c2 + 3], pk[tt][4 * c2 + 2], pk[tt][4 * c2 + 3]};
        bf16x8 pbf = __builtin_bit_cast(bf16x8, pb4);
        const int colb = tt * 64 + c2 * 32 + hh * 16;
#pragma unroll
        for (int dt = 0; dt < 4; dt++) {
          const int d = dt * 32 + l31;
          bf16x8 vf = *reinterpret_cast<const bf16x8*>(
              (const char*)Vs + d * 128 + (colb ^ ((d & 7) << 4)));
          o[dt] = __builtin_amdgcn_mfma_f32_32x32x16_bf16(vf, pbf, o[dt], 0, 0, 0);
        }
      }
    }
    __syncthreads();
  }

  lsum += __shfl_xor(lsum, 32);
  const float inv = 1.0f / lsum;
  char* my = asmem + wid * 8192;
#pragma unroll
  for (int dt = 0; dt < 4; dt++) {
#pragma unroll
    for (int j = 0; j < 8; j++) {
      const int r = 2 * j;
      const int d = dt * 32 + ((r & 3) + 8 * (r >> 2)) + 4 * hh;
      const unsigned int w = pack2(o[dt][r] * inv, o[dt][r + 1] * inv);
      *reinterpret_cast<unsigned int*>(my + ((l31 * 256 + d * 2) ^ ((l31 & 7) << 4))) = w;
    }
  }
#pragma unroll
  for (int j = 0; j < 8; j++) {
    const int idx = j * 64 + lane;
    const int row = idx >> 4, c16 = idx & 15;
    u32x4 val = *reinterpret_cast<u32x4*>(my + row * 256 + ((c16 * 16) ^ ((row & 7) << 4)));
    *reinterpret_cast<u32x4*>(Ob + (size_t)(b * S_LEN + qw + row) * (NH * HD) + h * HD + c16 * 8) = val;
  }
}

// ---------------- launch ----------------
extern "C" void kernel_launch(void* const* d_in, const int* in_sizes, int n_in,
                              void* d_out, int out_size, void* d_ws, size_t ws_size,
                              hipStream_t stream) {
  (void)in_sizes; (void)n_in; (void)out_size; (void)ws_size;
  const float* x    = (const float*)d_in[0];
  const float* wq_w = (const float*)d_in[1];
  const float* wq_b = (const float*)d_in[2];
  const float* wk_w = (const float*)d_in[3];
  const float* wk_b = (const float*)d_in[4];
  const float* wv_w = (const float*)d_in[5];
  const float* wv_b = (const float*)d_in[6];
  const float* wo_w = (const float*)d_in[7];
  const float* fcos = (const float*)d_in[10];
  const float* fsin = (const float*)d_in[11];
  const int*   spp  = (const int*)d_in[13];
  float* out = (float*)d_out;

  constexpr size_t XB_N = (size_t)4096 * 3584;
  constexpr size_t WQ_N = (size_t)3584 * 3584;
  constexpr size_t WK_N = (size_t)512 * 3584;
  constexpr size_t WO_N = (size_t)3584 * 3584;
  constexpr size_t KB_N = (size_t)4096 * 512;

  __bf16* xb  = (__bf16*)d_ws;
  __bf16* wqb = xb + XB_N;
  __bf16* wkb = wqb + WQ_N;
  __bf16* wvb = wkb + WK_N;
  __bf16* wob = wvb + WK_N;
  __bf16* Qb  = wob + WO_N;
  __bf16* Kb  = Qb + XB_N;
  __bf16* Vg  = Kb + KB_N;
  __bf16* Vt  = Vg + KB_N;
  __bf16* Ob  = xb;  // alias: xb dead after QKV GEMMs (stream-ordered)

  auto cvt = [&](const float* src, __bf16* dst, size_t n) {
    int n4 = (int)(n / 4);
    cvt_kernel<<<(n4 + 255) / 256, 256, 0, stream>>>(src, dst, n4);
  };
  cvt(x, xb, XB_N);
  cvt(wq_w, wqb, WQ_N);
  cvt(wk_w, wkb, WK_N);
  cvt(wv_w, wvb, WK_N);
  cvt(wo_w, wob, WO_N);

  gemm256<2><<<dim3(224), 512, 131072, stream>>>(xb, wqb, wq_b, Qb, 4096, 3584, 3584,
                                                 fcos, fsin, spp, SCALE_LOG2);
  gemm_bt<2><<<dim3(4, 32), 256, 0, stream>>>(xb, wkb, wk_b, Kb, 4096, 512, 3584,
                                              fcos, fsin, spp, 1.0f);
  gemm_bt<1><<<dim3(4, 32), 256, 0, stream>>>(xb, wvb, wv_b, Vg, 4096, 512, 3584,
                                              nullptr, nullptr, nullptr, 1.0f);
  vtrans_kernel<<<dim3(64, 4, 8), 256, 0, stream>>>(Vg, Vt);
  attn_kernel<<<dim3(16, 28, 2), 256, 0, stream>>>(Qb, Kb, Vt, Ob);
  gemm256<0><<<dim3(224), 512, 131072, stream>>>(Ob, wob, nullptr, out, 4096, 3584, 3584,
                                                 nullptr, nullptr, nullptr, 1.0f);
}

// Round 4
// 519.167 us; speedup vs baseline: 1.6512x; 1.1546x over previous
//
#include <hip/hip_runtime.h>
#include <hip/hip_bf16.h>

typedef __attribute__((ext_vector_type(4)))  float  f32x4;
typedef __attribute__((ext_vector_type(16))) float  f32x16;
typedef __attribute__((ext_vector_type(8)))  __bf16 bf16x8;
typedef __attribute__((ext_vector_type(4)))  __bf16 bf16x4;
typedef __attribute__((ext_vector_type(4)))  unsigned int u32x4;

constexpr int S_LEN = 2048, DMODEL = 3584, NH = 28, NKV = 4, HD = 128, NREP = 7;
// 128^-0.5 * log2(e): softmax computed in base-2 (exp2f == bare v_exp_f32)
constexpr float SCALE_LOG2 = 0.1275174331f;

__device__ __forceinline__ unsigned int pack2(float a, float b) {
  unsigned short ua = __builtin_bit_cast(unsigned short, (__bf16)a);
  unsigned short ub = __builtin_bit_cast(unsigned short, (__bf16)b);
  return (unsigned int)ua | ((unsigned int)ub << 16);
}

// ---------------- f32 -> bf16 convert, x4 vectorized ----------------
__global__ void cvt_kernel(const float* __restrict__ in, __bf16* __restrict__ out, int n4) {
  int i = blockIdx.x * blockDim.x + threadIdx.x;
  if (i >= n4) return;
  float4 v = reinterpret_cast<const float4*>(in)[i];
  bf16x4 o;
  o[0] = (__bf16)v.x; o[1] = (__bf16)v.y; o[2] = (__bf16)v.z; o[3] = (__bf16)v.w;
  reinterpret_cast<bf16x4*>(out)[i] = o;
}

#define GLDS16(gsrc, ldst)                                                              \
  __builtin_amdgcn_global_load_lds((const __attribute__((address_space(1))) void*)(gsrc),\
                                   (__attribute__((address_space(3))) void*)(ldst), 16, 0, 0)

// ============ 256x256 phased GEMM: C = A @ B^T (+bias) (+RoPE) ============
template <int MODE>
__global__ __launch_bounds__(512, 2) void gemm256(
    const __bf16* __restrict__ A, const __bf16* __restrict__ Bw,
    const float* __restrict__ bias, void* __restrict__ Cout,
    int M, int N, int K,
    const float* __restrict__ fcos, const float* __restrict__ fsin,
    const int* __restrict__ sp_ptr, float scale)
{
  extern __shared__ char smem[];  // [0,64K): A slots[4][16K]; [64K,128K): B slots[4][16K]
  const int tid = threadIdx.x;
  const int lane = tid & 63, wid = tid >> 6;
  const int wm = wid >> 2, wn = wid & 3;
  const int l15 = lane & 15, g = (lane >> 4) & 3;

  const int chunk = gridDim.x >> 3;
  const int wg = (blockIdx.x & 7) * chunk + (blockIdx.x >> 3);
  const int nbx = N >> 8;
  const int by = wg / nbx, bx = wg % nbx;
  const int row0 = by * 256, col0 = bx * 256;

  const int srL   = 16 * (tid >> 6) + ((tid >> 2) & 15);
  const int cperm = ((tid & 3) * 8) ^ (((tid >> 5) & 1) * 16);
  const __bf16* pA0 = A + (size_t)(row0 + srL) * K + cperm;
  const __bf16* pA1 = pA0 + (size_t)128 * K;
  const __bf16* pB0 = Bw + (size_t)(col0 + srL) * K + cperm;
  const __bf16* pB1 = pB0 + (size_t)128 * K;
  char* ldsA = smem + tid * 16;
  char* ldsB = smem + 65536 + tid * 16;

  const int sw = ((l15 >> 3) & 1) << 5;
  const int aoff = wm * 8192 + l15 * 64 + ((g * 16) ^ sw);
  const int boff = 65536 + wn * 4096 + l15 * 64 + ((g * 16) ^ sw);

  f32x4 acc[8][4] = {};
  const int nt = K >> 5;

#pragma unroll
  for (int pt = 0; pt < 3; pt++) {
    const size_t ko = (size_t)pt * 32;
    char* sA = ldsA + pt * 16384;
    char* sB = ldsB + pt * 16384;
    GLDS16(pA0 + ko, sA);
    GLDS16(pA1 + ko, sA + 8192);
    GLDS16(pB0 + ko, sB);
    GLDS16(pB1 + ko, sB + 8192);
  }
  asm volatile("s_waitcnt vmcnt(8)" ::: "memory");
  __builtin_amdgcn_s_barrier();
  __builtin_amdgcn_sched_barrier(0);

  for (int t = 0; t < nt; t++) {
    const int slot = (t & 3) * 16384;
    const char* sa = smem + slot + aoff;
    const char* sb = smem + slot + boff;
    bf16x8 af[4], bfv[4];

#pragma unroll
    for (int fm = 0; fm < 4; fm++)
      af[fm] = *reinterpret_cast<const bf16x8*>(sa + fm * 1024);
#pragma unroll
    for (int fn = 0; fn < 4; fn++)
      bfv[fn] = *reinterpret_cast<const bf16x8*>(sb + fn * 1024);
    if (t + 3 < nt) {
      const size_t ko = (size_t)(t + 3) * 32;
      char* sA = ldsA + ((t + 3) & 3) * 16384;
      GLDS16(pA0 + ko, sA);
      GLDS16(pA1 + ko, sA + 8192);
    }
    asm volatile("s_waitcnt lgkmcnt(0)" ::: "memory");
    __builtin_amdgcn_sched_barrier(0);
    __builtin_amdgcn_s_setprio(1);
#pragma unroll
    for (int fn = 0; fn < 4; fn++)
#pragma unroll
      for (int fm = 0; fm < 4; fm++)
        acc[fm][fn] = __builtin_amdgcn_mfma_f32_16x16x32_bf16(af[fm], bfv[fn], acc[fm][fn], 0, 0, 0);
    __builtin_amdgcn_s_setprio(0);
    __builtin_amdgcn_s_barrier();
    __builtin_amdgcn_sched_barrier(0);

#pragma unroll
    for (int fm = 0; fm < 4; fm++)
      af[fm] = *reinterpret_cast<const bf16x8*>(sa + (4 + fm) * 1024);
    if (t + 3 < nt) {
      const size_t ko = (size_t)(t + 3) * 32;
      char* sB = ldsB + ((t + 3) & 3) * 16384;
      GLDS16(pB0 + ko, sB);
      GLDS16(pB1 + ko, sB + 8192);
    }
    asm volatile("s_waitcnt lgkmcnt(0)" ::: "memory");
    __builtin_amdgcn_sched_barrier(0);
    __builtin_amdgcn_s_setprio(1);
#pragma unroll
    for (int fn = 0; fn < 4; fn++)
#pragma unroll
      for (int fm = 0; fm < 4; fm++)
        acc[4 + fm][fn] = __builtin_amdgcn_mfma_f32_16x16x32_bf16(af[fm], bfv[fn], acc[4 + fm][fn], 0, 0, 0);
    __builtin_amdgcn_s_setprio(0);

    if (t < nt - 3)       asm volatile("s_waitcnt vmcnt(8)" ::: "memory");
    else if (t == nt - 3) asm volatile("s_waitcnt vmcnt(4)" ::: "memory");
    else if (t == nt - 2) asm volatile("s_waitcnt vmcnt(0)" ::: "memory");
    __builtin_amdgcn_s_barrier();
    __builtin_amdgcn_sched_barrier(0);
  }

  if constexpr (MODE == 0) {
    float* C = (float*)Cout;
#pragma unroll
    for (int fm = 0; fm < 8; fm++) {
      const int row = row0 + wm * 128 + fm * 16 + 4 * g;
#pragma unroll
      for (int fn = 0; fn < 4; fn++) {
        const int col = col0 + wn * 64 + fn * 16 + l15;
#pragma unroll
        for (int r = 0; r < 4; r++)
          C[(size_t)(row + r) * N + col] = acc[fm][fn][r];
      }
    }
  } else {
    __bf16* C = (__bf16*)Cout;
    const int sp = sp_ptr[0];
    float bval[4];
#pragma unroll
    for (int fn = 0; fn < 4; fn++) bval[fn] = bias[col0 + wn * 64 + fn * 16 + l15];
#pragma unroll
    for (int fm = 0; fm < 8; fm++) {
#pragma unroll
      for (int fn = 0; fn < 4; fn++) {
        const int col = col0 + wn * 64 + fn * 16 + l15;
        const int i = (col & (HD - 1)) >> 1;
#pragma unroll
        for (int r = 0; r < 4; r++) {
          const int row = row0 + wm * 128 + fm * 16 + 4 * g + r;
          float y = acc[fm][fn][r] + bval[fn];
          float p = __shfl_xor(y, 1);
          const int spos = sp + (row & (S_LEN - 1));
          const float c = fcos[spos * (HD / 2) + i];
          const float sn = fsin[spos * (HD / 2) + i];
          y = (col & 1) ? (p * sn + y * c) : (y * c - p * sn);
          C[(size_t)row * N + col] = (__bf16)(y * scale);
        }
      }
    }
  }
}

// ---------------- fused K+V projection GEMM (N=512 each, one dispatch) ----------------
// blockIdx.x < 4: K projection (bias + RoPE); >= 4: V projection (bias only).
__global__ __launch_bounds__(256) void gemm_kv(
    const __bf16* __restrict__ A,
    const __bf16* __restrict__ Wk, const float* __restrict__ bk, __bf16* __restrict__ Ko,
    const __bf16* __restrict__ Wv, const float* __restrict__ bv, __bf16* __restrict__ Vo,
    const float* __restrict__ fcos, const float* __restrict__ fsin,
    const int* __restrict__ sp_ptr)
{
  constexpr int N = 512, K = 3584;
  __shared__ __bf16 As[128 * 32];
  __shared__ __bf16 Bs[128 * 32];
  const int tid = threadIdx.x;
  const int lane = tid & 63, wid = tid >> 6;
  const int l15 = lane & 15, g = lane >> 4;
  const int wr = wid >> 1, wc = wid & 1;
  const bool isK = blockIdx.x < 4;
  const __bf16* Bw = isK ? Wk : Wv;
  const float* bias = isK ? bk : bv;
  __bf16* Cout = isK ? Ko : Vo;
  const int row0 = blockIdx.y * 128;
  const int col0 = (blockIdx.x & 3) * 128;

  f32x4 acc[4][4] = {};

  const int srow = tid >> 2;
  const int scol = (tid & 3) * 8;
  const __bf16* Ag0 = A + (size_t)(row0 + srow) * K + scol;
  const __bf16* Ag1 = Ag0 + (size_t)64 * K;
  const __bf16* Bg0 = Bw + (size_t)(col0 + srow) * K + scol;
  const __bf16* Bg1 = Bg0 + (size_t)64 * K;
  __bf16* As0 = As + tid * 8;
  __bf16* As1 = As + 2048 + tid * 8;
  __bf16* Bs0 = Bs + tid * 8;
  __bf16* Bs1 = Bs + 2048 + tid * 8;

  for (int k0 = 0; k0 < K; k0 += 32) {
    GLDS16(Ag0 + k0, As0);
    GLDS16(Ag1 + k0, As1);
    GLDS16(Bg0 + k0, Bs0);
    GLDS16(Bg1 + k0, Bs1);
    __syncthreads();
    bf16x8 af[4], bfr[4];
#pragma unroll
    for (int m = 0; m < 4; m++)
      af[m] = *reinterpret_cast<const bf16x8*>(As + (wr * 64 + m * 16 + l15) * 32 + g * 8);
#pragma unroll
    for (int n = 0; n < 4; n++)
      bfr[n] = *reinterpret_cast<const bf16x8*>(Bs + (wc * 64 + n * 16 + l15) * 32 + g * 8);
#pragma unroll
    for (int m = 0; m < 4; m++)
#pragma unroll
      for (int n = 0; n < 4; n++)
        acc[m][n] = __builtin_amdgcn_mfma_f32_16x16x32_bf16(af[m], bfr[n], acc[m][n], 0, 0, 0);
    __syncthreads();
  }

  const int sp = sp_ptr[0];
#pragma unroll
  for (int m = 0; m < 4; m++) {
#pragma unroll
    for (int n = 0; n < 4; n++) {
      const int col = col0 + wc * 64 + n * 16 + l15;
      const float bval = bias[col];
      f32x4 v = acc[m][n];
#pragma unroll
      for (int r = 0; r < 4; r++) {
        const int row = row0 + wr * 64 + m * 16 + 4 * g + r;
        float y = v[r] + bval;
        if (isK) {
          float p = __shfl_xor(y, 1);
          const int i = (col & (HD - 1)) >> 1;
          const int spos = sp + (row & (S_LEN - 1));
          const float c = fcos[spos * (HD / 2) + i];
          const float sn = fsin[spos * (HD / 2) + i];
          y = (col & 1) ? (p * sn + y * c) : (y * c - p * sn);
        }
        Cout[(size_t)row * N + col] = (__bf16)y;
      }
    }
  }
}

// ---------------- V transpose: (B,S,KV,HD) bf16 -> (B,KV,HD,S) bf16 ----------------
__global__ void vtrans_kernel(const __bf16* __restrict__ Vg, __bf16* __restrict__ Vt) {
  __shared__ __bf16 t[32][33];
  const int bkv = blockIdx.z;
  const int b = bkv >> 2, kv = bkv & 3;
  const int s0 = blockIdx.x * 32, h0 = blockIdx.y * 32;
  const int tid = threadIdx.x;
#pragma unroll
  for (int c = 0; c < 4; c++) {
    int idx = c * 256 + tid;
    int sr = idx >> 5, hc = idx & 31;
    t[sr][hc] = Vg[(((size_t)b * S_LEN + s0 + sr) * NKV + kv) * HD + h0 + hc];
  }
  __syncthreads();
#pragma unroll
  for (int c = 0; c < 4; c++) {
    int idx = c * 256 + tid;
    int hr = idx >> 5, sc = idx & 31;
    Vt[(((size_t)b * NKV + kv) * HD + h0 + hr) * S_LEN + s0 + sc] = t[sc][hr];
  }
}

// ---------------- Flash attention: 32x32 MFMA, dbuf K/V, 1 barrier/tile ----------------
__global__ __launch_bounds__(256, 2) void attn_kernel(
    const __bf16* __restrict__ Qb, const __bf16* __restrict__ Kb,
    const __bf16* __restrict__ Vt, __bf16* __restrict__ Ob)
{
  // slot s (s=0,1): Ks at s*32768 ([64][128] swz), Vs at s*32768+16384 ([128][64] swz)
  __shared__ __align__(16) char asmem[65536];

  const int tid = threadIdx.x, lane = tid & 63, wid = tid >> 6;
  const int l31 = lane & 31, hh = lane >> 5;
  const int b = blockIdx.z, h = blockIdx.y;
  const int kvh = h / NREP;
  const int qi = 15 - blockIdx.x;        // biggest causal blocks first
  const int qw = qi * 128 + wid * 32;
  const int qg = qw + l31;

  bf16x8 qf[8];
  {
    const __bf16* qp = Qb + (((size_t)b * S_LEN + qg) * NH + h) * HD + hh * 8;
#pragma unroll
    for (int c = 0; c < 8; c++) qf[c] = *reinterpret_cast<const bf16x8*>(qp + c * 16);
  }

  f32x16 o[4] = {};
  float mrun = -3.0e38f, lsum = 0.0f;

  const __bf16* Kbase = Kb + ((size_t)b * S_LEN * NKV + kvh) * HD;
  const __bf16* Vbase = Vt + ((size_t)b * NKV + kvh) * (size_t)HD * S_LEN;

  // staging maps: linear LDS dest, pre-swizzled global source (rule 21 / m173)
  const int trow = tid >> 4;
  const int kcol = (((tid & 15) * 16) ^ ((trow & 7) << 4)) >> 1;
  const int vrow = tid >> 3;
  const int vcol = (((tid & 7) * 16) ^ ((vrow & 7) << 4)) >> 1;

  const int ntiles = 2 * qi + 2;  // always even -> last tile reads slot 1

#define STAGE(T, S)                                                                     \
  do {                                                                                  \
    const int k0_ = (T) * 64;                                                           \
    char* Kd_ = asmem + (S) * 32768;                                                    \
    char* Vd_ = Kd_ + 16384;                                                            \
    _Pragma("unroll")                                                                   \
    for (int p = 0; p < 4; p++) {                                                       \
      GLDS16(Kbase + (size_t)(k0_ + p * 16 + trow) * (NKV * HD) + kcol,                 \
             Kd_ + (p * 256 + tid) * 16);                                               \
      GLDS16(Vbase + (size_t)(p * 32 + vrow) * S_LEN + k0_ + vcol,                      \
             Vd_ + (p * 256 + tid) * 16);                                               \
    }                                                                                   \
  } while (0)

  STAGE(0, 0);

  for (int t = 0; t < ntiles; t++) {
    // drains tile t's staging loads (they had tile t-1's compute to land) + joins waves
    __syncthreads();
    if (t + 1 < ntiles) STAGE(t + 1, (t + 1) & 1);

    const char* Ksb = asmem + (t & 1) * 32768;
    const char* Vsb = Ksb + 16384;
    const int k0 = t * 64;

    // ---- S^T[kv 64][q 32] = K . Q^T
    f32x16 s0 = {}, s1 = {};
    {
      const char* kp0 = Ksb + l31 * 256;
      const char* kp1 = kp0 + 32 * 256;
      const int sw = (l31 & 7) << 4;
      __builtin_amdgcn_s_setprio(1);
#pragma unroll
      for (int c = 0; c < 8; c++) {
        const int cb = (c * 32 + hh * 16) ^ sw;
        bf16x8 kf0 = *reinterpret_cast<const bf16x8*>(kp0 + cb);
        s0 = __builtin_amdgcn_mfma_f32_32x32x16_bf16(kf0, qf[c], s0, 0, 0, 0);
        bf16x8 kf1 = *reinterpret_cast<const bf16x8*>(kp1 + cb);
        s1 = __builtin_amdgcn_mfma_f32_32x32x16_bf16(kf1, qf[c], s1, 0, 0, 0);
      }
      __builtin_amdgcn_s_setprio(0);
    }

    // ---- causal mask (boundary tiles only)
    if (k0 + 63 > qw) {
#pragma unroll
      for (int r = 0; r < 16; r++) {
        const int kvo = k0 + ((r & 3) + 8 * (r >> 2)) + 4 * hh;
        if (kvo > qg)      s0[r] = -1.0e9f;
        if (kvo + 32 > qg) s1[r] = -1.0e9f;
      }
    }

    // ---- online softmax (base-2), defer-max (T13)
    float pmax = -3.0e38f;
#pragma unroll
    for (int r = 0; r < 16; r++) { pmax = fmaxf(pmax, s0[r]); pmax = fmaxf(pmax, s1[r]); }
    pmax = fmaxf(pmax, __shfl_xor(pmax, 32));
    if (!__all(pmax <= mrun + 11.5f)) {
      const float mnew = fmaxf(mrun, pmax);
      const float fs = exp2f(mrun - mnew);
      lsum *= fs;
#pragma unroll
      for (int dt = 0; dt < 4; dt++) o[dt] *= fs;
      mrun = mnew;
    }
    float psum = 0.0f;
#pragma unroll
    for (int r = 0; r < 16; r++) {
      s0[r] = exp2f(s0[r] - mrun); psum += s0[r];
      s1[r] = exp2f(s1[r] - mrun); psum += s1[r];
    }
    lsum += psum;

    // ---- pack P to bf16 + cross-half exchange
    unsigned int pk[2][8], px[2][8];
#pragma unroll
    for (int j = 0; j < 8; j++) {
      pk[0][j] = pack2(s0[2 * j], s0[2 * j + 1]);
      pk[1][j] = pack2(s1[2 * j], s1[2 * j + 1]);
    }
#pragma unroll
    for (int tt = 0; tt < 2; tt++)
#pragma unroll
      for (int j = 0; j < 8; j++) px[tt][j] = __shfl_xor(pk[tt][j], 32);

    // ---- O^T += V^T . P^T
    __builtin_amdgcn_s_setprio(1);
#pragma unroll
    for (int tt = 0; tt < 2; tt++) {
#pragma unroll
      for (int c2 = 0; c2 < 2; c2++) {
        u32x4 pb4;
        if (hh == 0)
          pb4 = (u32x4){pk[tt][4 * c2], pk[tt][4 * c2 + 1], px[tt][4 * c2], px[tt][4 * c2 + 1]};
        else
          pb4 = (u32x4){px[tt][4 * c2 + 2], px[tt][4 * c2 + 3], pk[tt][4 * c2 + 2], pk[tt][4 * c2 + 3]};
        bf16x8 pbf = __builtin_bit_cast(bf16x8, pb4);
        const int colb = tt * 64 + c2 * 32 + hh * 16;
#pragma unroll
        for (int dt = 0; dt < 4; dt++) {
          const int d = dt * 32 + l31;
          bf16x8 vf = *reinterpret_cast<const bf16x8*>(Vsb + d * 128 + (colb ^ ((d & 7) << 4)));
          o[dt] = __builtin_amdgcn_mfma_f32_32x32x16_bf16(vf, pbf, o[dt], 0, 0, 0);
        }
      }
    }
    __builtin_amdgcn_s_setprio(0);
  }
#undef STAGE

  // ---- epilogue: normalize, transpose O^T -> O via warp-local slot-0 LDS (disjoint
  // from slot-1, which the last tile read; ntiles even guarantees that)
  lsum += __shfl_xor(lsum, 32);
  const float inv = 1.0f / lsum;
  char* my = asmem + wid * 8192;
#pragma unroll
  for (int dt = 0; dt < 4; dt++) {
#pragma unroll
    for (int j = 0; j < 8; j++) {
      const int r = 2 * j;
      const int d = dt * 32 + ((r & 3) + 8 * (r >> 2)) + 4 * hh;
      const unsigned int w = pack2(o[dt][r] * inv, o[dt][r + 1] * inv);
      *reinterpret_cast<unsigned int*>(my + ((l31 * 256 + d * 2) ^ ((l31 & 7) << 4))) = w;
    }
  }
#pragma unroll
  for (int j = 0; j < 8; j++) {
    const int idx = j * 64 + lane;
    const int row = idx >> 4, c16 = idx & 15;
    u32x4 val = *reinterpret_cast<u32x4*>(my + row * 256 + ((c16 * 16) ^ ((row & 7) << 4)));
    *reinterpret_cast<u32x4*>(Ob + (size_t)(b * S_LEN + qw + row) * (NH * HD) + h * HD + c16 * 8) = val;
  }
}

// ---------------- launch ----------------
extern "C" void kernel_launch(void* const* d_in, const int* in_sizes, int n_in,
                              void* d_out, int out_size, void* d_ws, size_t ws_size,
                              hipStream_t stream) {
  (void)in_sizes; (void)n_in; (void)out_size; (void)ws_size;
  const float* x    = (const float*)d_in[0];
  const float* wq_w = (const float*)d_in[1];
  const float* wq_b = (const float*)d_in[2];
  const float* wk_w = (const float*)d_in[3];
  const float* wk_b = (const float*)d_in[4];
  const float* wv_w = (const float*)d_in[5];
  const float* wv_b = (const float*)d_in[6];
  const float* wo_w = (const float*)d_in[7];
  const float* fcos = (const float*)d_in[10];
  const float* fsin = (const float*)d_in[11];
  const int*   spp  = (const int*)d_in[13];
  float* out = (float*)d_out;

  constexpr size_t XB_N = (size_t)4096 * 3584;
  constexpr size_t WQ_N = (size_t)3584 * 3584;
  constexpr size_t WK_N = (size_t)512 * 3584;
  constexpr size_t WO_N = (size_t)3584 * 3584;
  constexpr size_t KB_N = (size_t)4096 * 512;

  __bf16* xb  = (__bf16*)d_ws;
  __bf16* wqb = xb + XB_N;
  __bf16* wkb = wqb + WQ_N;
  __bf16* wvb = wkb + WK_N;
  __bf16* wob = wvb + WK_N;
  __bf16* Qb  = wob + WO_N;
  __bf16* Kb  = Qb + XB_N;
  __bf16* Vg  = Kb + KB_N;
  __bf16* Vt  = Vg + KB_N;
  __bf16* Ob  = xb;  // alias: xb dead after QKV GEMMs (stream-ordered)

  auto cvt = [&](const float* src, __bf16* dst, size_t n) {
    int n4 = (int)(n / 4);
    cvt_kernel<<<(n4 + 255) / 256, 256, 0, stream>>>(src, dst, n4);
  };
  cvt(x, xb, XB_N);
  cvt(wq_w, wqb, WQ_N);
  cvt(wk_w, wkb, WK_N);
  cvt(wv_w, wvb, WK_N);
  cvt(wo_w, wob, WO_N);

  gemm256<2><<<dim3(224), 512, 131072, stream>>>(xb, wqb, wq_b, Qb, 4096, 3584, 3584,
                                                 fcos, fsin, spp, SCALE_LOG2);
  gemm_kv<<<dim3(8, 32), 256, 0, stream>>>(xb, wkb, wk_b, Kb, wvb, wv_b, Vg,
                                           fcos, fsin, spp);
  vtrans_kernel<<<dim3(64, 4, 8), 256, 0, stream>>>(Vg, Vt);
  attn_kernel<<<dim3(16, 28, 2), 256, 0, stream>>>(Qb, Kb, Vt, Ob);
  gemm256<0><<<dim3(224), 512, 131072, stream>>>(Ob, wob, nullptr, out, 4096, 3584, 3584,
                                                 nullptr, nullptr, nullptr, 1.0f);
}

// Round 5
// 450.826 us; speedup vs baseline: 1.9015x; 1.1516x over previous
//
#include <hip/hip_runtime.h>
#include <hip/hip_bf16.h>

typedef __attribute__((ext_vector_type(4)))  float  f32x4;
typedef __attribute__((ext_vector_type(16))) float  f32x16;
typedef __attribute__((ext_vector_type(8)))  __bf16 bf16x8;
typedef __attribute__((ext_vector_type(4)))  __bf16 bf16x4;
typedef __attribute__((ext_vector_type(4)))  unsigned int u32x4;

constexpr int S_LEN = 2048, DMODEL = 3584, NH = 28, NKV = 4, HD = 128, NREP = 7;
// 128^-0.5 * log2(e): softmax computed in base-2 (exp2f == bare v_exp_f32)
constexpr float SCALE_LOG2 = 0.1275174331f;

__device__ __forceinline__ unsigned int pack2(float a, float b) {
  unsigned short ua = __builtin_bit_cast(unsigned short, (__bf16)a);
  unsigned short ub = __builtin_bit_cast(unsigned short, (__bf16)b);
  return (unsigned int)ua | ((unsigned int)ub << 16);
}

// ---------------- f32 -> bf16 convert, x4 vectorized ----------------
__global__ void cvt_kernel(const float* __restrict__ in, __bf16* __restrict__ out, int n4) {
  int i = blockIdx.x * blockDim.x + threadIdx.x;
  if (i >= n4) return;
  float4 v = reinterpret_cast<const float4*>(in)[i];
  bf16x4 o;
  o[0] = (__bf16)v.x; o[1] = (__bf16)v.y; o[2] = (__bf16)v.z; o[3] = (__bf16)v.w;
  reinterpret_cast<bf16x4*>(out)[i] = o;
}

__global__ void zero_ctr_kernel(int* p) { *p = 0; }

#define GLDS16(gsrc, ldst)                                                              \
  __builtin_amdgcn_global_load_lds((const __attribute__((address_space(1))) void*)(gsrc),\
                                   (__attribute__((address_space(3))) void*)(ldst), 16, 0, 0)

// ============ 256x256 phased GEMM: C = A @ B^T (+bias) (+RoPE) ============
template <int MODE>
__global__ __launch_bounds__(512, 2) void gemm256(
    const __bf16* __restrict__ A, const __bf16* __restrict__ Bw,
    const float* __restrict__ bias, void* __restrict__ Cout,
    int M, int N, int K,
    const float* __restrict__ fcos, const float* __restrict__ fsin,
    const int* __restrict__ sp_ptr, float scale)
{
  extern __shared__ char smem[];  // [0,64K): A slots[4][16K]; [64K,128K): B slots[4][16K]
  const int tid = threadIdx.x;
  const int lane = tid & 63, wid = tid >> 6;
  const int wm = wid >> 2, wn = wid & 3;
  const int l15 = lane & 15, g = (lane >> 4) & 3;

  const int chunk = gridDim.x >> 3;
  const int wg = (blockIdx.x & 7) * chunk + (blockIdx.x >> 3);
  const int nbx = N >> 8;
  const int by = wg / nbx, bx = wg % nbx;
  const int row0 = by * 256, col0 = bx * 256;

  const int srL   = 16 * (tid >> 6) + ((tid >> 2) & 15);
  const int cperm = ((tid & 3) * 8) ^ (((tid >> 5) & 1) * 16);
  const __bf16* pA0 = A + (size_t)(row0 + srL) * K + cperm;
  const __bf16* pA1 = pA0 + (size_t)128 * K;
  const __bf16* pB0 = Bw + (size_t)(col0 + srL) * K + cperm;
  const __bf16* pB1 = pB0 + (size_t)128 * K;
  char* ldsA = smem + tid * 16;
  char* ldsB = smem + 65536 + tid * 16;

  const int sw = ((l15 >> 3) & 1) << 5;
  const int aoff = wm * 8192 + l15 * 64 + ((g * 16) ^ sw);
  const int boff = 65536 + wn * 4096 + l15 * 64 + ((g * 16) ^ sw);

  f32x4 acc[8][4] = {};
  const int nt = K >> 5;

#pragma unroll
  for (int pt = 0; pt < 3; pt++) {
    const size_t ko = (size_t)pt * 32;
    char* sA = ldsA + pt * 16384;
    char* sB = ldsB + pt * 16384;
    GLDS16(pA0 + ko, sA);
    GLDS16(pA1 + ko, sA + 8192);
    GLDS16(pB0 + ko, sB);
    GLDS16(pB1 + ko, sB + 8192);
  }
  asm volatile("s_waitcnt vmcnt(8)" ::: "memory");
  __builtin_amdgcn_s_barrier();
  __builtin_amdgcn_sched_barrier(0);

  for (int t = 0; t < nt; t++) {
    const int slot = (t & 3) * 16384;
    const char* sa = smem + slot + aoff;
    const char* sb = smem + slot + boff;
    bf16x8 af[4], bfv[4];

#pragma unroll
    for (int fm = 0; fm < 4; fm++)
      af[fm] = *reinterpret_cast<const bf16x8*>(sa + fm * 1024);
#pragma unroll
    for (int fn = 0; fn < 4; fn++)
      bfv[fn] = *reinterpret_cast<const bf16x8*>(sb + fn * 1024);
    if (t + 3 < nt) {
      const size_t ko = (size_t)(t + 3) * 32;
      char* sA = ldsA + ((t + 3) & 3) * 16384;
      GLDS16(pA0 + ko, sA);
      GLDS16(pA1 + ko, sA + 8192);
    }
    asm volatile("s_waitcnt lgkmcnt(0)" ::: "memory");
    __builtin_amdgcn_sched_barrier(0);
    __builtin_amdgcn_s_setprio(1);
#pragma unroll
    for (int fn = 0; fn < 4; fn++)
#pragma unroll
      for (int fm = 0; fm < 4; fm++)
        acc[fm][fn] = __builtin_amdgcn_mfma_f32_16x16x32_bf16(af[fm], bfv[fn], acc[fm][fn], 0, 0, 0);
    __builtin_amdgcn_s_setprio(0);
    __builtin_amdgcn_s_barrier();
    __builtin_amdgcn_sched_barrier(0);

#pragma unroll
    for (int fm = 0; fm < 4; fm++)
      af[fm] = *reinterpret_cast<const bf16x8*>(sa + (4 + fm) * 1024);
    if (t + 3 < nt) {
      const size_t ko = (size_t)(t + 3) * 32;
      char* sB = ldsB + ((t + 3) & 3) * 16384;
      GLDS16(pB0 + ko, sB);
      GLDS16(pB1 + ko, sB + 8192);
    }
    asm volatile("s_waitcnt lgkmcnt(0)" ::: "memory");
    __builtin_amdgcn_sched_barrier(0);
    __builtin_amdgcn_s_setprio(1);
#pragma unroll
    for (int fn = 0; fn < 4; fn++)
#pragma unroll
      for (int fm = 0; fm < 4; fm++)
        acc[4 + fm][fn] = __builtin_amdgcn_mfma_f32_16x16x32_bf16(af[fm], bfv[fn], acc[4 + fm][fn], 0, 0, 0);
    __builtin_amdgcn_s_setprio(0);

    if (t < nt - 3)       asm volatile("s_waitcnt vmcnt(8)" ::: "memory");
    else if (t == nt - 3) asm volatile("s_waitcnt vmcnt(4)" ::: "memory");
    else if (t == nt - 2) asm volatile("s_waitcnt vmcnt(0)" ::: "memory");
    __builtin_amdgcn_s_barrier();
    __builtin_amdgcn_sched_barrier(0);
  }

  if constexpr (MODE == 0) {
    float* C = (float*)Cout;
#pragma unroll
    for (int fm = 0; fm < 8; fm++) {
      const int row = row0 + wm * 128 + fm * 16 + 4 * g;
#pragma unroll
      for (int fn = 0; fn < 4; fn++) {
        const int col = col0 + wn * 64 + fn * 16 + l15;
#pragma unroll
        for (int r = 0; r < 4; r++)
          C[(size_t)(row + r) * N + col] = acc[fm][fn][r];
      }
    }
  } else {
    __bf16* C = (__bf16*)Cout;
    const int sp = sp_ptr[0];
    float bval[4];
#pragma unroll
    for (int fn = 0; fn < 4; fn++) bval[fn] = bias[col0 + wn * 64 + fn * 16 + l15];
#pragma unroll
    for (int fm = 0; fm < 8; fm++) {
#pragma unroll
      for (int fn = 0; fn < 4; fn++) {
        const int col = col0 + wn * 64 + fn * 16 + l15;
        const int i = (col & (HD - 1)) >> 1;
#pragma unroll
        for (int r = 0; r < 4; r++) {
          const int row = row0 + wm * 128 + fm * 16 + 4 * g + r;
          float y = acc[fm][fn][r] + bval[fn];
          float p = __shfl_xor(y, 1);
          const int spos = sp + (row & (S_LEN - 1));
          const float c = fcos[spos * (HD / 2) + i];
          const float sn = fsin[spos * (HD / 2) + i];
          y = (col & 1) ? (p * sn + y * c) : (y * c - p * sn);
          C[(size_t)row * N + col] = (__bf16)(y * scale);
        }
      }
    }
  }
}

// ---------------- fused K+V projection GEMM (N=512 each, one dispatch) ----------------
__global__ __launch_bounds__(256) void gemm_kv(
    const __bf16* __restrict__ A,
    const __bf16* __restrict__ Wk, const float* __restrict__ bk, __bf16* __restrict__ Ko,
    const __bf16* __restrict__ Wv, const float* __restrict__ bv, __bf16* __restrict__ Vo,
    const float* __restrict__ fcos, const float* __restrict__ fsin,
    const int* __restrict__ sp_ptr)
{
  constexpr int N = 512, K = 3584;
  __shared__ __bf16 As[128 * 32];
  __shared__ __bf16 Bs[128 * 32];
  const int tid = threadIdx.x;
  const int lane = tid & 63, wid = tid >> 6;
  const int l15 = lane & 15, g = lane >> 4;
  const int wr = wid >> 1, wc = wid & 1;
  const bool isK = blockIdx.x < 4;
  const __bf16* Bw = isK ? Wk : Wv;
  const float* bias = isK ? bk : bv;
  __bf16* Cout = isK ? Ko : Vo;
  const int row0 = blockIdx.y * 128;
  const int col0 = (blockIdx.x & 3) * 128;

  f32x4 acc[4][4] = {};

  const int srow = tid >> 2;
  const int scol = (tid & 3) * 8;
  const __bf16* Ag0 = A + (size_t)(row0 + srow) * K + scol;
  const __bf16* Ag1 = Ag0 + (size_t)64 * K;
  const __bf16* Bg0 = Bw + (size_t)(col0 + srow) * K + scol;
  const __bf16* Bg1 = Bg0 + (size_t)64 * K;
  __bf16* As0 = As + tid * 8;
  __bf16* As1 = As + 2048 + tid * 8;
  __bf16* Bs0 = Bs + tid * 8;
  __bf16* Bs1 = Bs + 2048 + tid * 8;

  for (int k0 = 0; k0 < K; k0 += 32) {
    GLDS16(Ag0 + k0, As0);
    GLDS16(Ag1 + k0, As1);
    GLDS16(Bg0 + k0, Bs0);
    GLDS16(Bg1 + k0, Bs1);
    __syncthreads();
    bf16x8 af[4], bfr[4];
#pragma unroll
    for (int m = 0; m < 4; m++)
      af[m] = *reinterpret_cast<const bf16x8*>(As + (wr * 64 + m * 16 + l15) * 32 + g * 8);
#pragma unroll
    for (int n = 0; n < 4; n++)
      bfr[n] = *reinterpret_cast<const bf16x8*>(Bs + (wc * 64 + n * 16 + l15) * 32 + g * 8);
#pragma unroll
    for (int m = 0; m < 4; m++)
#pragma unroll
      for (int n = 0; n < 4; n++)
        acc[m][n] = __builtin_amdgcn_mfma_f32_16x16x32_bf16(af[m], bfr[n], acc[m][n], 0, 0, 0);
    __syncthreads();
  }

  const int sp = sp_ptr[0];
#pragma unroll
  for (int m = 0; m < 4; m++) {
#pragma unroll
    for (int n = 0; n < 4; n++) {
      const int col = col0 + wc * 64 + n * 16 + l15;
      const float bval = bias[col];
      f32x4 v = acc[m][n];
#pragma unroll
      for (int r = 0; r < 4; r++) {
        const int row = row0 + wr * 64 + m * 16 + 4 * g + r;
        float y = v[r] + bval;
        if (isK) {
          float p = __shfl_xor(y, 1);
          const int i = (col & (HD - 1)) >> 1;
          const int spos = sp + (row & (S_LEN - 1));
          const float c = fcos[spos * (HD / 2) + i];
          const float sn = fsin[spos * (HD / 2) + i];
          y = (col & 1) ? (p * sn + y * c) : (y * c - p * sn);
        }
        Cout[(size_t)row * N + col] = (__bf16)y;
      }
    }
  }
}

// ---------------- V transpose: (B,S,KV,HD) bf16 -> (B,KV,HD,S) bf16 ----------------
__global__ void vtrans_kernel(const __bf16* __restrict__ Vg, __bf16* __restrict__ Vt) {
  __shared__ __bf16 t[32][33];
  const int bkv = blockIdx.z;
  const int b = bkv >> 2, kv = bkv & 3;
  const int s0 = blockIdx.x * 32, h0 = blockIdx.y * 32;
  const int tid = threadIdx.x;
#pragma unroll
  for (int c = 0; c < 4; c++) {
    int idx = c * 256 + tid;
    int sr = idx >> 5, hc = idx & 31;
    t[sr][hc] = Vg[(((size_t)b * S_LEN + s0 + sr) * NKV + kv) * HD + h0 + hc];
  }
  __syncthreads();
#pragma unroll
  for (int c = 0; c < 4; c++) {
    int idx = c * 256 + tid;
    int hr = idx >> 5, sc = idx & 31;
    Vt[(((size_t)b * NKV + kv) * HD + h0 + hr) * S_LEN + s0 + sc] = t[sc][hr];
  }
}

// -------- Flash attention: persistent blocks + LPT dynamic work queue --------
// 512 blocks (2/CU), 896 items = (qtile, h, b), qi descending (longest first).
__global__ __launch_bounds__(256, 2) void attn_kernel(
    const __bf16* __restrict__ Qb, const __bf16* __restrict__ Kb,
    const __bf16* __restrict__ Vt, __bf16* __restrict__ Ob, int* __restrict__ ctr)
{
  // slot s (s=0,1): Ks at s*32768 ([64][128] swz), Vs at s*32768+16384 ([128][64] swz)
  __shared__ __align__(16) char asmem[65536];
  __shared__ int jsh;

  const int tid = threadIdx.x, lane = tid & 63, wid = tid >> 6;
  const int l31 = lane & 31, hh = lane >> 5;

  // staging maps: linear LDS dest, pre-swizzled global source (rule 21 / m173)
  const int trow = tid >> 4;
  const int kcol = (((tid & 15) * 16) ^ ((trow & 7) << 4)) >> 1;
  const int vrow = tid >> 3;
  const int vcol = (((tid & 7) * 16) ^ ((vrow & 7) << 4)) >> 1;

  constexpr int NITEMS = 16 * NH * 2;  // 896

  while (true) {
    if (tid == 0) jsh = atomicAdd(ctr, 1);
    // barrier: broadcasts jsh AND fences prev item's epilogue LDS reads vs STAGE(0)
    __syncthreads();
    const int j = jsh;
    if (j >= NITEMS) break;

    const int qi = 15 - (j / 56);
    const int r56 = j % 56;
    const int h = r56 >> 1, b = r56 & 1;
    const int kvh = h / NREP;
    const int qw = qi * 128 + wid * 32;
    const int qg = qw + l31;

    const __bf16* Kbase = Kb + ((size_t)b * S_LEN * NKV + kvh) * HD;
    const __bf16* Vbase = Vt + ((size_t)b * NKV + kvh) * (size_t)HD * S_LEN;

    bf16x8 qf[8];
    {
      const __bf16* qp = Qb + (((size_t)b * S_LEN + qg) * NH + h) * HD + hh * 8;
#pragma unroll
      for (int c = 0; c < 8; c++) qf[c] = *reinterpret_cast<const bf16x8*>(qp + c * 16);
    }

    f32x16 o[4] = {};
    float mrun = -3.0e38f, lsum = 0.0f;

    const int ntiles = 2 * qi + 2;  // always even -> last tile reads slot 1

#define STAGE(T, S)                                                                     \
    do {                                                                                \
      const int k0_ = (T) * 64;                                                         \
      char* Kd_ = asmem + (S) * 32768;                                                  \
      char* Vd_ = Kd_ + 16384;                                                          \
      _Pragma("unroll")                                                                 \
      for (int p = 0; p < 4; p++) {                                                     \
        GLDS16(Kbase + (size_t)(k0_ + p * 16 + trow) * (NKV * HD) + kcol,               \
               Kd_ + (p * 256 + tid) * 16);                                             \
        GLDS16(Vbase + (size_t)(p * 32 + vrow) * S_LEN + k0_ + vcol,                    \
               Vd_ + (p * 256 + tid) * 16);                                             \
      }                                                                                 \
    } while (0)

    STAGE(0, 0);

    for (int t = 0; t < ntiles; t++) {
      __syncthreads();  // drains tile t's staging loads + joins waves
      if (t + 1 < ntiles) STAGE(t + 1, (t + 1) & 1);

      const char* Ksb = asmem + (t & 1) * 32768;
      const char* Vsb = Ksb + 16384;
      const int k0 = t * 64;

      // ---- S^T[kv 64][q 32] = K . Q^T
      f32x16 s0 = {}, s1 = {};
      {
        const char* kp0 = Ksb + l31 * 256;
        const char* kp1 = kp0 + 32 * 256;
        const int sw = (l31 & 7) << 4;
        __builtin_amdgcn_s_setprio(1);
#pragma unroll
        for (int c = 0; c < 8; c++) {
          const int cb = (c * 32 + hh * 16) ^ sw;
          bf16x8 kf0 = *reinterpret_cast<const bf16x8*>(kp0 + cb);
          s0 = __builtin_amdgcn_mfma_f32_32x32x16_bf16(kf0, qf[c], s0, 0, 0, 0);
          bf16x8 kf1 = *reinterpret_cast<const bf16x8*>(kp1 + cb);
          s1 = __builtin_amdgcn_mfma_f32_32x32x16_bf16(kf1, qf[c], s1, 0, 0, 0);
        }
        __builtin_amdgcn_s_setprio(0);
      }

      // ---- causal mask (boundary tiles only)
      if (k0 + 63 > qw) {
#pragma unroll
        for (int r = 0; r < 16; r++) {
          const int kvo = k0 + ((r & 3) + 8 * (r >> 2)) + 4 * hh;
          if (kvo > qg)      s0[r] = -1.0e9f;
          if (kvo + 32 > qg) s1[r] = -1.0e9f;
        }
      }

      // ---- online softmax (base-2), defer-max (T13)
      float pmax = -3.0e38f;
#pragma unroll
      for (int r = 0; r < 16; r++) { pmax = fmaxf(pmax, s0[r]); pmax = fmaxf(pmax, s1[r]); }
      pmax = fmaxf(pmax, __shfl_xor(pmax, 32));
      if (!__all(pmax <= mrun + 11.5f)) {
        const float mnew = fmaxf(mrun, pmax);
        const float fs = exp2f(mrun - mnew);
        lsum *= fs;
#pragma unroll
        for (int dt = 0; dt < 4; dt++) o[dt] *= fs;
        mrun = mnew;
      }
      float psum = 0.0f;
#pragma unroll
      for (int r = 0; r < 16; r++) {
        s0[r] = exp2f(s0[r] - mrun); psum += s0[r];
        s1[r] = exp2f(s1[r] - mrun); psum += s1[r];
      }
      lsum += psum;

      // ---- pack P to bf16 + cross-half exchange
      unsigned int pk[2][8], px[2][8];
#pragma unroll
      for (int jj = 0; jj < 8; jj++) {
        pk[0][jj] = pack2(s0[2 * jj], s0[2 * jj + 1]);
        pk[1][jj] = pack2(s1[2 * jj], s1[2 * jj + 1]);
      }
#pragma unroll
      for (int tt = 0; tt < 2; tt++)
#pragma unroll
        for (int jj = 0; jj < 8; jj++) px[tt][jj] = __shfl_xor(pk[tt][jj], 32);

      // ---- O^T += V^T . P^T
      __builtin_amdgcn_s_setprio(1);
#pragma unroll
      for (int tt = 0; tt < 2; tt++) {
#pragma unroll
        for (int c2 = 0; c2 < 2; c2++) {
          u32x4 pb4;
          if (hh == 0)
            pb4 = (u32x4){pk[tt][4 * c2], pk[tt][4 * c2 + 1], px[tt][4 * c2], px[tt][4 * c2 + 1]};
          else
            pb4 = (u32x4){px[tt][4 * c2 + 2], px[tt][4 * c2 + 3], pk[tt][4 * c2 + 2], pk[tt][4 * c2 + 3]};
          bf16x8 pbf = __builtin_bit_cast(bf16x8, pb4);
          const int colb = tt * 64 + c2 * 32 + hh * 16;
#pragma unroll
          for (int dt = 0; dt < 4; dt++) {
            const int d = dt * 32 + l31;
            bf16x8 vf = *reinterpret_cast<const bf16x8*>(Vsb + d * 128 + (colb ^ ((d & 7) << 4)));
            o[dt] = __builtin_amdgcn_mfma_f32_32x32x16_bf16(vf, pbf, o[dt], 0, 0, 0);
          }
        }
      }
      __builtin_amdgcn_s_setprio(0);
    }
#undef STAGE

    // ---- epilogue: normalize, transpose O^T -> O via warp-local slot-0 LDS
    // (disjoint from slot-1, which the last tile read; ntiles even guarantees that)
    lsum += __shfl_xor(lsum, 32);
    const float inv = 1.0f / lsum;
    char* my = asmem + wid * 8192;
#pragma unroll
    for (int dt = 0; dt < 4; dt++) {
#pragma unroll
      for (int jj = 0; jj < 8; jj++) {
        const int r = 2 * jj;
        const int d = dt * 32 + ((r & 3) + 8 * (r >> 2)) + 4 * hh;
        const unsigned int w = pack2(o[dt][r] * inv, o[dt][r + 1] * inv);
        *reinterpret_cast<unsigned int*>(my + ((l31 * 256 + d * 2) ^ ((l31 & 7) << 4))) = w;
      }
    }
#pragma unroll
    for (int jj = 0; jj < 8; jj++) {
      const int idx = jj * 64 + lane;
      const int row = idx >> 4, c16 = idx & 15;
      u32x4 val = *reinterpret_cast<u32x4*>(my + row * 256 + ((c16 * 16) ^ ((row & 7) << 4)));
      *reinterpret_cast<u32x4*>(Ob + (size_t)(b * S_LEN + qw + row) * (NH * HD) + h * HD + c16 * 8) = val;
    }
  }
}

// ---------------- launch ----------------
extern "C" void kernel_launch(void* const* d_in, const int* in_sizes, int n_in,
                              void* d_out, int out_size, void* d_ws, size_t ws_size,
                              hipStream_t stream) {
  (void)in_sizes; (void)n_in; (void)out_size; (void)ws_size;
  const float* x    = (const float*)d_in[0];
  const float* wq_w = (const float*)d_in[1];
  const float* wq_b = (const float*)d_in[2];
  const float* wk_w = (const float*)d_in[3];
  const float* wk_b = (const float*)d_in[4];
  const float* wv_w = (const float*)d_in[5];
  const float* wv_b = (const float*)d_in[6];
  const float* wo_w = (const float*)d_in[7];
  const float* fcos = (const float*)d_in[10];
  const float* fsin = (const float*)d_in[11];
  const int*   spp  = (const int*)d_in[13];
  float* out = (float*)d_out;

  constexpr size_t XB_N = (size_t)4096 * 3584;
  constexpr size_t WQ_N = (size_t)3584 * 3584;
  constexpr size_t WK_N = (size_t)512 * 3584;
  constexpr size_t WO_N = (size_t)3584 * 3584;
  constexpr size_t KB_N = (size_t)4096 * 512;

  __bf16* xb  = (__bf16*)d_ws;
  __bf16* wqb = xb + XB_N;
  __bf16* wkb = wqb + WQ_N;
  __bf16* wvb = wkb + WK_N;
  __bf16* wob = wvb + WK_N;
  __bf16* Qb  = wob + WO_N;
  __bf16* Kb  = Qb + XB_N;
  __bf16* Vg  = Kb + KB_N;
  __bf16* Vt  = Vg + KB_N;
  int*    ctr = (int*)(Vt + KB_N);
  __bf16* Ob  = xb;  // alias: xb dead after QKV GEMMs (stream-ordered)

  auto cvt = [&](const float* src, __bf16* dst, size_t n) {
    int n4 = (int)(n / 4);
    cvt_kernel<<<(n4 + 255) / 256, 256, 0, stream>>>(src, dst, n4);
  };
  cvt(x, xb, XB_N);
  cvt(wq_w, wqb, WQ_N);
  cvt(wk_w, wkb, WK_N);
  cvt(wv_w, wvb, WK_N);
  cvt(wo_w, wob, WO_N);
  zero_ctr_kernel<<<1, 1, 0, stream>>>(ctr);

  gemm256<2><<<dim3(224), 512, 131072, stream>>>(xb, wqb, wq_b, Qb, 4096, 3584, 3584,
                                                 fcos, fsin, spp, SCALE_LOG2);
  gemm_kv<<<dim3(8, 32), 256, 0, stream>>>(xb, wkb, wk_b, Kb, wvb, wv_b, Vg,
                                           fcos, fsin, spp);
  vtrans_kernel<<<dim3(64, 4, 8), 256, 0, stream>>>(Vg, Vt);
  attn_kernel<<<dim3(512), 256, 0, stream>>>(Qb, Kb, Vt, Ob, ctr);
  gemm256<0><<<dim3(224), 512, 131072, stream>>>(Ob, wob, nullptr, out, 4096, 3584, 3584,
                                                 nullptr, nullptr, nullptr, 1.0f);
}

// Round 6
// 432.931 us; speedup vs baseline: 1.9801x; 1.0413x over previous
//
#include <hip/hip_runtime.h>
#include <hip/hip_bf16.h>

typedef __attribute__((ext_vector_type(4)))  float  f32x4;
typedef __attribute__((ext_vector_type(16))) float  f32x16;
typedef __attribute__((ext_vector_type(8)))  __bf16 bf16x8;
typedef __attribute__((ext_vector_type(4)))  __bf16 bf16x4;
typedef __attribute__((ext_vector_type(4)))  unsigned int u32x4;

constexpr int S_LEN = 2048, DMODEL = 3584, NH = 28, NKV = 4, HD = 128, NREP = 7;
// 128^-0.5 * log2(e): softmax computed in base-2 (exp2f == bare v_exp_f32)
constexpr float SCALE_LOG2 = 0.1275174331f;

__device__ __forceinline__ unsigned int pack2(float a, float b) {
  unsigned short ua = __builtin_bit_cast(unsigned short, (__bf16)a);
  unsigned short ub = __builtin_bit_cast(unsigned short, (__bf16)b);
  return (unsigned int)ua | ((unsigned int)ub << 16);
}

// ---------------- fused f32 -> bf16 convert (5 tensors) + ctr zero ----------------
__global__ void cvt5_kernel(const float* __restrict__ s0, const float* __restrict__ s1,
                            const float* __restrict__ s2, const float* __restrict__ s3,
                            const float* __restrict__ s4,
                            __bf16* __restrict__ d0, __bf16* __restrict__ d1,
                            __bf16* __restrict__ d2, __bf16* __restrict__ d3,
                            __bf16* __restrict__ d4,
                            int n0, int n1, int n2, int n3, int* __restrict__ ctr, int total) {
  if (blockIdx.x == 0 && threadIdx.x == 0) *ctr = 0;
  for (int i = blockIdx.x * blockDim.x + threadIdx.x; i < total; i += gridDim.x * blockDim.x) {
    const float* s; __bf16* d; int j = i;
    if (j < n0) { s = s0; d = d0; }
    else { j -= n0;
      if (j < n1) { s = s1; d = d1; }
      else { j -= n1;
        if (j < n2) { s = s2; d = d2; }
        else { j -= n2;
          if (j < n3) { s = s3; d = d3; }
          else { j -= n3; s = s4; d = d4; }
        }
      }
    }
    float4 v = reinterpret_cast<const float4*>(s)[j];
    bf16x4 o;
    o[0] = (__bf16)v.x; o[1] = (__bf16)v.y; o[2] = (__bf16)v.z; o[3] = (__bf16)v.w;
    reinterpret_cast<bf16x4*>(d)[j] = o;
  }
}

#define GLDS16(gsrc, ldst)                                                              \
  __builtin_amdgcn_global_load_lds((const __attribute__((address_space(1))) void*)(gsrc),\
                                   (__attribute__((address_space(3))) void*)(ldst), 16, 0, 0)

// ============ 256x256 phased GEMM: C = A @ B^T (+bias) (+RoPE) ============
// 8 waves (2M x 4N), BK=32, 4-slot LDS ring (128 KiB), counted vmcnt(8),
// ONE barrier per K-tile (ring distance-3 makes the mid-tile barrier unnecessary),
// counted lgkmcnt(4) so quadrant-1's ds_reads hide under quadrant-0's MFMAs.
template <int MODE>
__global__ __launch_bounds__(512, 2) void gemm256(
    const __bf16* __restrict__ A, const __bf16* __restrict__ Bw,
    const float* __restrict__ bias, void* __restrict__ Cout,
    int M, int N, int K,
    const float* __restrict__ fcos, const float* __restrict__ fsin,
    const int* __restrict__ sp_ptr, float scale)
{
  extern __shared__ char smem[];  // [0,64K): A slots[4][16K]; [64K,128K): B slots[4][16K]
  const int tid = threadIdx.x;
  const int lane = tid & 63, wid = tid >> 6;
  const int wm = wid >> 2, wn = wid & 3;
  const int l15 = lane & 15, g = (lane >> 4) & 3;

  const int chunk = gridDim.x >> 3;
  const int wg = (blockIdx.x & 7) * chunk + (blockIdx.x >> 3);
  const int nbx = N >> 8;
  const int by = wg / nbx, bx = wg % nbx;
  const int row0 = by * 256, col0 = bx * 256;

  const int srL   = 16 * (tid >> 6) + ((tid >> 2) & 15);
  const int cperm = ((tid & 3) * 8) ^ (((tid >> 5) & 1) * 16);
  const __bf16* pA0 = A + (size_t)(row0 + srL) * K + cperm;
  const __bf16* pA1 = pA0 + (size_t)128 * K;
  const __bf16* pB0 = Bw + (size_t)(col0 + srL) * K + cperm;
  const __bf16* pB1 = pB0 + (size_t)128 * K;
  char* ldsA = smem + tid * 16;
  char* ldsB = smem + 65536 + tid * 16;

  const int sw = ((l15 >> 3) & 1) << 5;
  const int aoff = wm * 8192 + l15 * 64 + ((g * 16) ^ sw);
  const int boff = 65536 + wn * 4096 + l15 * 64 + ((g * 16) ^ sw);

  f32x4 acc[8][4] = {};
  const int nt = K >> 5;

#pragma unroll
  for (int pt = 0; pt < 3; pt++) {
    const size_t ko = (size_t)pt * 32;
    char* sA = ldsA + pt * 16384;
    char* sB = ldsB + pt * 16384;
    GLDS16(pA0 + ko, sA);
    GLDS16(pA1 + ko, sA + 8192);
    GLDS16(pB0 + ko, sB);
    GLDS16(pB1 + ko, sB + 8192);
  }
  asm volatile("s_waitcnt vmcnt(8)" ::: "memory");   // tile 0 resident
  __builtin_amdgcn_s_barrier();
  __builtin_amdgcn_sched_barrier(0);

  for (int t = 0; t < nt; t++) {
    const int slot = (t & 3) * 16384;
    const char* sa = smem + slot + aoff;
    const char* sb = smem + slot + boff;
    bf16x8 a0[4], a1[4], bfv[4];

    // ---- issue all 12 ds_reads (oldest 8 = B + A-lo feed quadrant 0) ----
#pragma unroll
    for (int fn = 0; fn < 4; fn++)
      bfv[fn] = *reinterpret_cast<const bf16x8*>(sb + fn * 1024);
#pragma unroll
    for (int fm = 0; fm < 4; fm++)
      a0[fm] = *reinterpret_cast<const bf16x8*>(sa + fm * 1024);
#pragma unroll
    for (int fm = 0; fm < 4; fm++)
      a1[fm] = *reinterpret_cast<const bf16x8*>(sa + (4 + fm) * 1024);

    // ---- stage tile t+3 into slot (t-1)&3 (its readers all drained lgkm
    //      before the end-of-(t-1) barrier; safe with one barrier/tile) ----
    if (t + 3 < nt) {
      const size_t ko = (size_t)(t + 3) * 32;
      char* sA = ldsA + ((t + 3) & 3) * 16384;
      char* sB = ldsB + ((t + 3) & 3) * 16384;
      GLDS16(pA0 + ko, sA);
      GLDS16(pA1 + ko, sA + 8192);
      GLDS16(pB0 + ko, sB);
      GLDS16(pB1 + ko, sB + 8192);
    }

    asm volatile("s_waitcnt lgkmcnt(4)" ::: "memory");
    __builtin_amdgcn_sched_barrier(0);
    __builtin_amdgcn_s_setprio(1);
#pragma unroll
    for (int fn = 0; fn < 4; fn++)
#pragma unroll
      for (int fm = 0; fm < 4; fm++)
        acc[fm][fn] = __builtin_amdgcn_mfma_f32_16x16x32_bf16(a0[fm], bfv[fn], acc[fm][fn], 0, 0, 0);
    __builtin_amdgcn_s_setprio(0);

    asm volatile("s_waitcnt lgkmcnt(0)" ::: "memory");
    __builtin_amdgcn_sched_barrier(0);
    __builtin_amdgcn_s_setprio(1);
#pragma unroll
    for (int fn = 0; fn < 4; fn++)
#pragma unroll
      for (int fm = 0; fm < 4; fm++)
        acc[4 + fm][fn] = __builtin_amdgcn_mfma_f32_16x16x32_bf16(a1[fm], bfv[fn], acc[4 + fm][fn], 0, 0, 0);
    __builtin_amdgcn_s_setprio(0);

    // ---- tile boundary: counted drain (tile t+1 resident; keep 8 in flight) ----
    if (t < nt - 3)       asm volatile("s_waitcnt vmcnt(8)" ::: "memory");
    else if (t == nt - 3) asm volatile("s_waitcnt vmcnt(4)" ::: "memory");
    else if (t == nt - 2) asm volatile("s_waitcnt vmcnt(0)" ::: "memory");
    __builtin_amdgcn_s_barrier();
    __builtin_amdgcn_sched_barrier(0);
  }

  if constexpr (MODE == 0) {
    float* C = (float*)Cout;
#pragma unroll
    for (int fm = 0; fm < 8; fm++) {
      const int row = row0 + wm * 128 + fm * 16 + 4 * g;
#pragma unroll
      for (int fn = 0; fn < 4; fn++) {
        const int col = col0 + wn * 64 + fn * 16 + l15;
#pragma unroll
        for (int r = 0; r < 4; r++)
          C[(size_t)(row + r) * N + col] = acc[fm][fn][r];
      }
    }
  } else {
    __bf16* C = (__bf16*)Cout;
    const int sp = sp_ptr[0];
    float bval[4];
#pragma unroll
    for (int fn = 0; fn < 4; fn++) bval[fn] = bias[col0 + wn * 64 + fn * 16 + l15];
#pragma unroll
    for (int fm = 0; fm < 8; fm++) {
#pragma unroll
      for (int fn = 0; fn < 4; fn++) {
        const int col = col0 + wn * 64 + fn * 16 + l15;
        const int i = (col & (HD - 1)) >> 1;
#pragma unroll
        for (int r = 0; r < 4; r++) {
          const int row = row0 + wm * 128 + fm * 16 + 4 * g + r;
          float y = acc[fm][fn][r] + bval[fn];
          float p = __shfl_xor(y, 1);
          const int spos = sp + (row & (S_LEN - 1));
          const float c = fcos[spos * (HD / 2) + i];
          const float sn = fsin[spos * (HD / 2) + i];
          y = (col & 1) ? (p * sn + y * c) : (y * c - p * sn);
          C[(size_t)row * N + col] = (__bf16)(y * scale);
        }
      }
    }
  }
}

// ---------------- fused K+V projection GEMM (N=512 each, one dispatch) ----------------
__global__ __launch_bounds__(256) void gemm_kv(
    const __bf16* __restrict__ A,
    const __bf16* __restrict__ Wk, const float* __restrict__ bk, __bf16* __restrict__ Ko,
    const __bf16* __restrict__ Wv, const float* __restrict__ bv, __bf16* __restrict__ Vo,
    const float* __restrict__ fcos, const float* __restrict__ fsin,
    const int* __restrict__ sp_ptr)
{
  constexpr int N = 512, K = 3584;
  __shared__ __bf16 As[128 * 32];
  __shared__ __bf16 Bs[128 * 32];
  const int tid = threadIdx.x;
  const int lane = tid & 63, wid = tid >> 6;
  const int l15 = lane & 15, g = lane >> 4;
  const int wr = wid >> 1, wc = wid & 1;
  const bool isK = blockIdx.x < 4;
  const __bf16* Bw = isK ? Wk : Wv;
  const float* bias = isK ? bk : bv;
  __bf16* Cout = isK ? Ko : Vo;
  const int row0 = blockIdx.y * 128;
  const int col0 = (blockIdx.x & 3) * 128;

  f32x4 acc[4][4] = {};

  const int srow = tid >> 2;
  const int scol = (tid & 3) * 8;
  const __bf16* Ag0 = A + (size_t)(row0 + srow) * K + scol;
  const __bf16* Ag1 = Ag0 + (size_t)64 * K;
  const __bf16* Bg0 = Bw + (size_t)(col0 + srow) * K + scol;
  const __bf16* Bg1 = Bg0 + (size_t)64 * K;
  __bf16* As0 = As + tid * 8;
  __bf16* As1 = As + 2048 + tid * 8;
  __bf16* Bs0 = Bs + tid * 8;
  __bf16* Bs1 = Bs + 2048 + tid * 8;

  for (int k0 = 0; k0 < K; k0 += 32) {
    GLDS16(Ag0 + k0, As0);
    GLDS16(Ag1 + k0, As1);
    GLDS16(Bg0 + k0, Bs0);
    GLDS16(Bg1 + k0, Bs1);
    __syncthreads();
    bf16x8 af[4], bfr[4];
#pragma unroll
    for (int m = 0; m < 4; m++)
      af[m] = *reinterpret_cast<const bf16x8*>(As + (wr * 64 + m * 16 + l15) * 32 + g * 8);
#pragma unroll
    for (int n = 0; n < 4; n++)
      bfr[n] = *reinterpret_cast<const bf16x8*>(Bs + (wc * 64 + n * 16 + l15) * 32 + g * 8);
#pragma unroll
    for (int m = 0; m < 4; m++)
#pragma unroll
      for (int n = 0; n < 4; n++)
        acc[m][n] = __builtin_amdgcn_mfma_f32_16x16x32_bf16(af[m], bfr[n], acc[m][n], 0, 0, 0);
    __syncthreads();
  }

  const int sp = sp_ptr[0];
#pragma unroll
  for (int m = 0; m < 4; m++) {
#pragma unroll
    for (int n = 0; n < 4; n++) {
      const int col = col0 + wc * 64 + n * 16 + l15;
      const float bval = bias[col];
      f32x4 v = acc[m][n];
#pragma unroll
      for (int r = 0; r < 4; r++) {
        const int row = row0 + wr * 64 + m * 16 + 4 * g + r;
        float y = v[r] + bval;
        if (isK) {
          float p = __shfl_xor(y, 1);
          const int i = (col & (HD - 1)) >> 1;
          const int spos = sp + (row & (S_LEN - 1));
          const float c = fcos[spos * (HD / 2) + i];
          const float sn = fsin[spos * (HD / 2) + i];
          y = (col & 1) ? (p * sn + y * c) : (y * c - p * sn);
        }
        Cout[(size_t)row * N + col] = (__bf16)y;
      }
    }
  }
}

// ---------------- V transpose: (B,S,KV,HD) bf16 -> (B,KV,HD,S) bf16 ----------------
__global__ void vtrans_kernel(const __bf16* __restrict__ Vg, __bf16* __restrict__ Vt) {
  __shared__ __bf16 t[32][33];
  const int bkv = blockIdx.z;
  const int b = bkv >> 2, kv = bkv & 3;
  const int s0 = blockIdx.x * 32, h0 = blockIdx.y * 32;
  const int tid = threadIdx.x;
#pragma unroll
  for (int c = 0; c < 4; c++) {
    int idx = c * 256 + tid;
    int sr = idx >> 5, hc = idx & 31;
    t[sr][hc] = Vg[(((size_t)b * S_LEN + s0 + sr) * NKV + kv) * HD + h0 + hc];
  }
  __syncthreads();
#pragma unroll
  for (int c = 0; c < 4; c++) {
    int idx = c * 256 + tid;
    int hr = idx >> 5, sc = idx & 31;
    Vt[(((size_t)b * NKV + kv) * HD + h0 + hr) * S_LEN + s0 + sc] = t[sc][hr];
  }
}

// -------- Flash attention: persistent blocks + LPT dynamic work queue --------
// 512 blocks (2/CU), 896 items = (qtile, h, b), qi descending (longest first).
__global__ __launch_bounds__(256, 2) void attn_kernel(
    const __bf16* __restrict__ Qb, const __bf16* __restrict__ Kb,
    const __bf16* __restrict__ Vt, __bf16* __restrict__ Ob, int* __restrict__ ctr)
{
  // slot s (s=0,1): Ks at s*32768 ([64][128] swz), Vs at s*32768+16384 ([128][64] swz)
  __shared__ __align__(16) char asmem[65536];
  __shared__ int jsh;

  const int tid = threadIdx.x, lane = tid & 63, wid = tid >> 6;
  const int l31 = lane & 31, hh = lane >> 5;

  const int trow = tid >> 4;
  const int kcol = (((tid & 15) * 16) ^ ((trow & 7) << 4)) >> 1;
  const int vrow = tid >> 3;
  const int vcol = (((tid & 7) * 16) ^ ((vrow & 7) << 4)) >> 1;

  constexpr int NITEMS = 16 * NH * 2;  // 896

  while (true) {
    if (tid == 0) jsh = atomicAdd(ctr, 1);
    __syncthreads();
    const int j = jsh;
    if (j >= NITEMS) break;

    const int qi = 15 - (j / 56);
    const int r56 = j % 56;
    const int h = r56 >> 1, b = r56 & 1;
    const int kvh = h / NREP;
    const int qw = qi * 128 + wid * 32;
    const int qg = qw + l31;

    const __bf16* Kbase = Kb + ((size_t)b * S_LEN * NKV + kvh) * HD;
    const __bf16* Vbase = Vt + ((size_t)b * NKV + kvh) * (size_t)HD * S_LEN;

    bf16x8 qf[8];
    {
      const __bf16* qp = Qb + (((size_t)b * S_LEN + qg) * NH + h) * HD + hh * 8;
#pragma unroll
      for (int c = 0; c < 8; c++) qf[c] = *reinterpret_cast<const bf16x8*>(qp + c * 16);
    }

    f32x16 o[4] = {};
    float mrun = -3.0e38f, lsum = 0.0f;

    const int ntiles = 2 * qi + 2;  // always even -> last tile reads slot 1

#define STAGE(T, S)                                                                     \
    do {                                                                                \
      const int k0_ = (T) * 64;                                                         \
      char* Kd_ = asmem + (S) * 32768;                                                  \
      char* Vd_ = Kd_ + 16384;                                                          \
      _Pragma("unroll")                                                                 \
      for (int p = 0; p < 4; p++) {                                                     \
        GLDS16(Kbase + (size_t)(k0_ + p * 16 + trow) * (NKV * HD) + kcol,               \
               Kd_ + (p * 256 + tid) * 16);                                             \
        GLDS16(Vbase + (size_t)(p * 32 + vrow) * S_LEN + k0_ + vcol,                    \
               Vd_ + (p * 256 + tid) * 16);                                             \
      }                                                                                 \
    } while (0)

    STAGE(0, 0);

    for (int t = 0; t < ntiles; t++) {
      __syncthreads();  // drains tile t's staging loads + joins waves
      if (t + 1 < ntiles) STAGE(t + 1, (t + 1) & 1);

      const char* Ksb = asmem + (t & 1) * 32768;
      const char* Vsb = Ksb + 16384;
      const int k0 = t * 64;

      f32x16 s0 = {}, s1 = {};
      {
        const char* kp0 = Ksb + l31 * 256;
        const char* kp1 = kp0 + 32 * 256;
        const int sw = (l31 & 7) << 4;
        __builtin_amdgcn_s_setprio(1);
#pragma unroll
        for (int c = 0; c < 8; c++) {
          const int cb = (c * 32 + hh * 16) ^ sw;
          bf16x8 kf0 = *reinterpret_cast<const bf16x8*>(kp0 + cb);
          s0 = __builtin_amdgcn_mfma_f32_32x32x16_bf16(kf0, qf[c], s0, 0, 0, 0);
          bf16x8 kf1 = *reinterpret_cast<const bf16x8*>(kp1 + cb);
          s1 = __builtin_amdgcn_mfma_f32_32x32x16_bf16(kf1, qf[c], s1, 0, 0, 0);
        }
        __builtin_amdgcn_s_setprio(0);
      }

      if (k0 + 63 > qw) {
#pragma unroll
        for (int r = 0; r < 16; r++) {
          const int kvo = k0 + ((r & 3) + 8 * (r >> 2)) + 4 * hh;
          if (kvo > qg)      s0[r] = -1.0e9f;
          if (kvo + 32 > qg) s1[r] = -1.0e9f;
        }
      }

      float pmax = -3.0e38f;
#pragma unroll
      for (int r = 0; r < 16; r++) { pmax = fmaxf(pmax, s0[r]); pmax = fmaxf(pmax, s1[r]); }
      pmax = fmaxf(pmax, __shfl_xor(pmax, 32));
      if (!__all(pmax <= mrun + 11.5f)) {
        const float mnew = fmaxf(mrun, pmax);
        const float fs = exp2f(mrun - mnew);
        lsum *= fs;
#pragma unroll
        for (int dt = 0; dt < 4; dt++) o[dt] *= fs;
        mrun = mnew;
      }
      float psum = 0.0f;
#pragma unroll
      for (int r = 0; r < 16; r++) {
        s0[r] = exp2f(s0[r] - mrun); psum += s0[r];
        s1[r] = exp2f(s1[r] - mrun); psum += s1[r];
      }
      lsum += psum;

      unsigned int pk[2][8], px[2][8];
#pragma unroll
      for (int jj = 0; jj < 8; jj++) {
        pk[0][jj] = pack2(s0[2 * jj], s0[2 * jj + 1]);
        pk[1][jj] = pack2(s1[2 * jj], s1[2 * jj + 1]);
      }
#pragma unroll
      for (int tt = 0; tt < 2; tt++)
#pragma unroll
        for (int jj = 0; jj < 8; jj++) px[tt][jj] = __shfl_xor(pk[tt][jj], 32);

      __builtin_amdgcn_s_setprio(1);
#pragma unroll
      for (int tt = 0; tt < 2; tt++) {
#pragma unroll
        for (int c2 = 0; c2 < 2; c2++) {
          u32x4 pb4;
          if (hh == 0)
            pb4 = (u32x4){pk[tt][4 * c2], pk[tt][4 * c2 + 1], px[tt][4 * c2], px[tt][4 * c2 + 1]};
          else
            pb4 = (u32x4){px[tt][4 * c2 + 2], px[tt][4 * c2 + 3], pk[tt][4 * c2 + 2], pk[tt][4 * c2 + 3]};
          bf16x8 pbf = __builtin_bit_cast(bf16x8, pb4);
          const int colb = tt * 64 + c2 * 32 + hh * 16;
#pragma unroll
          for (int dt = 0; dt < 4; dt++) {
            const int d = dt * 32 + l31;
            bf16x8 vf = *reinterpret_cast<const bf16x8*>(Vsb + d * 128 + (colb ^ ((d & 7) << 4)));
            o[dt] = __builtin_amdgcn_mfma_f32_32x32x16_bf16(vf, pbf, o[dt], 0, 0, 0);
          }
        }
      }
      __builtin_amdgcn_s_setprio(0);
    }
#undef STAGE

    lsum += __shfl_xor(lsum, 32);
    const float inv = 1.0f / lsum;
    char* my = asmem + wid * 8192;
#pragma unroll
    for (int dt = 0; dt < 4; dt++) {
#pragma unroll
      for (int jj = 0; jj < 8; jj++) {
        const int r = 2 * jj;
        const int d = dt * 32 + ((r & 3) + 8 * (r >> 2)) + 4 * hh;
        const unsigned int w = pack2(o[dt][r] * inv, o[dt][r + 1] * inv);
        *reinterpret_cast<unsigned int*>(my + ((l31 * 256 + d * 2) ^ ((l31 & 7) << 4))) = w;
      }
    }
#pragma unroll
    for (int jj = 0; jj < 8; jj++) {
      const int idx = jj * 64 + lane;
      const int row = idx >> 4, c16 = idx & 15;
      u32x4 val = *reinterpret_cast<u32x4*>(my + row * 256 + ((c16 * 16) ^ ((row & 7) << 4)));
      *reinterpret_cast<u32x4*>(Ob + (size_t)(b * S_LEN + qw + row) * (NH * HD) + h * HD + c16 * 8) = val;
    }
  }
}

// ---------------- launch ----------------
extern "C" void kernel_launch(void* const* d_in, const int* in_sizes, int n_in,
                              void* d_out, int out_size, void* d_ws, size_t ws_size,
                              hipStream_t stream) {
  (void)in_sizes; (void)n_in; (void)out_size; (void)ws_size;
  const float* x    = (const float*)d_in[0];
  const float* wq_w = (const float*)d_in[1];
  const float* wq_b = (const float*)d_in[2];
  const float* wk_w = (const float*)d_in[3];
  const float* wk_b = (const float*)d_in[4];
  const float* wv_w = (const float*)d_in[5];
  const float* wv_b = (const float*)d_in[6];
  const float* wo_w = (const float*)d_in[7];
  const float* fcos = (const float*)d_in[10];
  const float* fsin = (const float*)d_in[11];
  const int*   spp  = (const int*)d_in[13];
  float* out = (float*)d_out;

  constexpr size_t XB_N = (size_t)4096 * 3584;
  constexpr size_t WQ_N = (size_t)3584 * 3584;
  constexpr size_t WK_N = (size_t)512 * 3584;
  constexpr size_t WO_N = (size_t)3584 * 3584;
  constexpr size_t KB_N = (size_t)4096 * 512;

  __bf16* xb  = (__bf16*)d_ws;
  __bf16* wqb = xb + XB_N;
  __bf16* wkb = wqb + WQ_N;
  __bf16* wvb = wkb + WK_N;
  __bf16* wob = wvb + WK_N;
  __bf16* Qb  = wob + WO_N;
  __bf16* Kb  = Qb + XB_N;
  __bf16* Vg  = Kb + KB_N;
  __bf16* Vt  = Vg + KB_N;
  int*    ctr = (int*)(Vt + KB_N);
  __bf16* Ob  = xb;  // alias: xb dead after QKV GEMMs (stream-ordered)

  constexpr int N0 = (int)(XB_N / 4), N1 = (int)(WQ_N / 4), N2 = (int)(WK_N / 4),
                N3 = (int)(WK_N / 4), N4 = (int)(WO_N / 4);
  constexpr int NTOT = N0 + N1 + N2 + N3 + N4;
  cvt5_kernel<<<2048, 256, 0, stream>>>(x, wq_w, wk_w, wv_w, wo_w,
                                        xb, wqb, wkb, wvb, wob,
                                        N0, N1, N2, N3, ctr, NTOT);

  gemm256<2><<<dim3(224), 512, 131072, stream>>>(xb, wqb, wq_b, Qb, 4096, 3584, 3584,
                                                 fcos, fsin, spp, SCALE_LOG2);
  gemm_kv<<<dim3(8, 32), 256, 0, stream>>>(xb, wkb, wk_b, Kb, wvb, wv_b, Vg,
                                           fcos, fsin, spp);
  vtrans_kernel<<<dim3(64, 4, 8), 256, 0, stream>>>(Vg, Vt);
  attn_kernel<<<dim3(512), 256, 0, stream>>>(Qb, Kb, Vt, Ob, ctr);
  gemm256<0><<<dim3(224), 512, 131072, stream>>>(Ob, wob, nullptr, out, 4096, 3584, 3584,
                                                 nullptr, nullptr, nullptr, 1.0f);
}